// Round 7
// baseline (346.668 us; speedup 1.0000x reference)
//
#include <hip/hip_runtime.h>
#include <hip/hip_fp16.h>

#define NVOX_DIM 20
#define NVOX 8000
#define BN_EPS 1e-5f

#define NBUCK 1024        // buckets = col >> 8
#define BSHIFT 8
#define NODES_PER_BUCK 256
#define GEMM_BLOCKS 1024
#define XTRA_BLOCKS 64
#define CAP_NEW 8192      // slab slots/bucket (32 KB) -> reused as pooled u16 rows
#define CAP_OLD 5120
#define VCAP 88           // nodes/voxel capacity: mean 32.8, sigma 5.7, exp-max ~57
#define CSTRIDE 16        // cursor padding: one 64B line per bucket counter
#define VSTRIDE 4         // vcursor padding: 16B per voxel counter
#define BIN_EPB 16384     // edges per k_bin2 block

typedef _Float16 f16x8 __attribute__((ext_vector_type(8)));
typedef float f32x4 __attribute__((ext_vector_type(4)));

// order-preserving u16 key for half bits: neg -> ~b, pos -> b|0x8000
__device__ __forceinline__ unsigned short f2key(float v) {
    unsigned short hb = __half_as_ushort(__float2half(v));
    unsigned short m = (unsigned short)(0x8000u | (unsigned short)(-(int)(hb >> 15)));
    return (unsigned short)(hb ^ m);
}

__device__ __forceinline__ float key2f(unsigned int k) {
    unsigned short hb = (k & 0x8000u) ? (unsigned short)(k ^ 0x8000u)
                                      : (unsigned short)(0xFFFFu ^ k);
    __half_raw hr;
    hr.x = hb;
    return __half2float((__half)hr);
}

__device__ __forceinline__ f16x8 pack8(float4 a, float4 b) {
    f16x8 r;
    r[0] = (_Float16)a.x; r[1] = (_Float16)a.y; r[2] = (_Float16)a.z; r[3] = (_Float16)a.w;
    r[4] = (_Float16)b.x; r[5] = (_Float16)b.y; r[6] = (_Float16)b.z; r[7] = (_Float16)b.w;
    return r;
}

// one 16-row group: 8 MFMAs + stats + u16-key stores
__device__ __forceinline__ void gemm_step(int row0, f16x8 a0, f16x8 a1,
                                          const f16x8 (&bf)[4][2], const float (&bv)[4],
                                          float (&s)[4], float (&s2)[4],
                                          unsigned short* __restrict__ h16,
                                          int l15, int q) {
#pragma unroll
    for (int t4 = 0; t4 < 4; ++t4) {
        f32x4 acc = {bv[t4], bv[t4], bv[t4], bv[t4]};
        acc = __builtin_amdgcn_mfma_f32_16x16x32_f16(a0, bf[t4][0], acc, 0, 0, 0);
        acc = __builtin_amdgcn_mfma_f32_16x16x32_f16(a1, bf[t4][1], acc, 0, 0, 0);
        s[t4] += acc[0] + acc[1] + acc[2] + acc[3];
        s2[t4] = fmaf(acc[0], acc[0], s2[t4]);
        s2[t4] = fmaf(acc[1], acc[1], s2[t4]);
        s2[t4] = fmaf(acc[2], acc[2], s2[t4]);
        s2[t4] = fmaf(acc[3], acc[3], s2[t4]);
#pragma unroll
        for (int r = 0; r < 4; ++r) {
            h16[(size_t)(row0 + q * 4 + r) * 64 + t4 * 16 + l15] = f2key(acc[r]);
        }
    }
}

// ---------------- K-1: zero an int region (cursors) --------------------------
__global__ __launch_bounds__(256) void k_zero(int* __restrict__ p, int n) {
    int i = blockIdx.x * 256 + threadIdx.x;
    if (i < n) p[i] = 0;
}

// ---------------- K0 (NEW): GEMM + stats | node->voxel binning ---------------
// bid < GEMM_BLOCKS : h = x@W + b via MFMA -> u16 order keys + stat partials.
//   MLP fix: 2-way g-unroll issues 8 independent float4 loads before any MFMA
//   (was 4) — k0 was HBM-latency-bound at ~1 KB in flight/CU.
// bid >= GEMM_BLOCKS: node->voxel binning (reads only pos)
// Pooling raw h before BN+ReLU downstream is valid: scale > 0 => BN+ReLU
// monotone nondecreasing per channel, commutes with max.
__global__ __launch_bounds__(256, 5) void k0_gemm(const float* __restrict__ x,
                                                  const float* __restrict__ W,
                                                  const float* __restrict__ bias,
                                                  unsigned short* __restrict__ h16,
                                                  float* __restrict__ partials, int n16,
                                                  const float* __restrict__ pos,
                                                  int* __restrict__ vcursor,
                                                  int* __restrict__ vlist) {
    __shared__ float sW[4096];
    __shared__ float red[2][4][64];
    int t = threadIdx.x;
    int bid = blockIdx.x;

    if (bid >= GEMM_BLOCKS) {
        int zb = bid - GEMM_BLOCKS;
        int nNodes = n16 * 16;
        for (int nd = zb * 256 + t; nd < nNodes; nd += XTRA_BLOCKS * 256) {
            float px = pos[(size_t)nd * 3 + 0];
            float py = pos[(size_t)nd * 3 + 1];
            float pz = pos[(size_t)nd * 3 + 2];
            int v0 = min(max((int)floorf(px * 2.f), 0), NVOX_DIM - 1);
            int v1 = min(max((int)floorf(py * 2.f), 0), NVOX_DIM - 1);
            int v2 = min(max((int)floorf(pz * 2.f), 0), NVOX_DIM - 1);
            int vox = (v0 * NVOX_DIM + v1) * NVOX_DIM + v2;
            int idx = atomicAdd(&vcursor[vox * VSTRIDE], 1);
            if (idx < VCAP) vlist[vox * VCAP + idx] = nd;
        }
        return;
    }

    int gb = bid;
    for (int i = t; i < 4096; i += 256) sW[i] = W[i];
    __syncthreads();
    int lane = t & 63;
    int w = t >> 6;
    int l15 = lane & 15;
    int q = lane >> 4;

    f16x8 bf[4][2];
#pragma unroll
    for (int t4 = 0; t4 < 4; ++t4)
#pragma unroll
        for (int kb = 0; kb < 2; ++kb)
#pragma unroll
            for (int i = 0; i < 8; ++i)
                bf[t4][kb][i] = (_Float16)sW[(kb * 32 + q * 8 + i) * 64 + t4 * 16 + l15];
    float bv[4];
#pragma unroll
    for (int t4 = 0; t4 < 4; ++t4) bv[t4] = bias[t4 * 16 + l15];

    float s[4] = {0.f, 0.f, 0.f, 0.f}, s2[4] = {0.f, 0.f, 0.f, 0.f};

    // 4 row-groups per wave, processed as 2 passes of 2 groups each; all 8
    // loads of a pass issue before any dependent compute (MLP ~2.5x).
#pragma unroll
    for (int kk = 0; kk < 2; ++kk) {
        int gA = gb * 4 + w + kk * (GEMM_BLOCKS * 8);
        int gB = gA + GEMM_BLOCKS * 4;
        bool doA = gA < n16, doB = gB < n16;
        float4 A0, A1, A2, A3, B0, B1, B2, B3;
        if (doA) {
            const float* xpA = x + (size_t)(gA * 16 + l15) * 64 + q * 8;
            A0 = *(const float4*)(xpA);
            A1 = *(const float4*)(xpA + 4);
            A2 = *(const float4*)(xpA + 32);
            A3 = *(const float4*)(xpA + 36);
        }
        if (doB) {
            const float* xpB = x + (size_t)(gB * 16 + l15) * 64 + q * 8;
            B0 = *(const float4*)(xpB);
            B1 = *(const float4*)(xpB + 4);
            B2 = *(const float4*)(xpB + 32);
            B3 = *(const float4*)(xpB + 36);
        }
        if (doA) {
            gemm_step(gA * 16, pack8(A0, A1), pack8(A2, A3), bf, bv, s, s2, h16, l15, q);
        }
        if (doB) {
            gemm_step(gB * 16, pack8(B0, B1), pack8(B2, B3), bf, bv, s, s2, h16, l15, q);
        }
    }

#pragma unroll
    for (int t4 = 0; t4 < 4; ++t4) {
        s[t4] += __shfl_xor(s[t4], 16, 64);
        s[t4] += __shfl_xor(s[t4], 32, 64);
        s2[t4] += __shfl_xor(s2[t4], 16, 64);
        s2[t4] += __shfl_xor(s2[t4], 32, 64);
    }
    if (lane < 16) {
#pragma unroll
        for (int t4 = 0; t4 < 4; ++t4) {
            red[0][w][t4 * 16 + lane] = s[t4];
            red[1][w][t4 * 16 + lane] = s2[t4];
        }
    }
    __syncthreads();
    if (t < 128) {
        int c = t & 63;
        int which = t >> 6;
        float v = red[which][0][c] + red[which][1][c] + red[which][2][c] + red[which][3][c];
        partials[(size_t)gb * 128 + which * 64 + c] = v;
    }
}

// ---------------- K_bin2: full in-LDS partition, coalesced flush -------------
// 256 blocks x 16384 edges. Histogram -> scan -> LDS scatter -> per-wave
// contiguous run flush (~64 B runs at cursor offsets).
__global__ __launch_bounds__(1024) void k_bin2(const int* __restrict__ rows,
                                               const int* __restrict__ cols,
                                               int* __restrict__ cursor,
                                               unsigned int* __restrict__ pairs) {
    __shared__ unsigned int buf[BIN_EPB];  // 64 KB
    __shared__ int hist[NBUCK];
    __shared__ int wpos[NBUCK];
    __shared__ int gbase[NBUCK];
    __shared__ int wsum[16];
    int t = threadIdx.x;
    int lane = t & 63;
    int w = t >> 6;

    hist[t] = 0;
    __syncthreads();

    int base_e = blockIdx.x * BIN_EPB + t * 16;
    int r[16], c[16];
#pragma unroll
    for (int g4 = 0; g4 < 4; ++g4) {
        int e = base_e + g4 * 4;
        int4 r4 = *(const int4*)(rows + e);
        int4 c4 = *(const int4*)(cols + e);
        r[g4 * 4 + 0] = r4.x; c[g4 * 4 + 0] = c4.x;
        r[g4 * 4 + 1] = r4.y; c[g4 * 4 + 1] = c4.y;
        r[g4 * 4 + 2] = r4.z; c[g4 * 4 + 2] = c4.z;
        r[g4 * 4 + 3] = r4.w; c[g4 * 4 + 3] = c4.w;
    }
#pragma unroll
    for (int i = 0; i < 16; ++i) atomicAdd(&hist[c[i] >> BSHIFT], 1);
    __syncthreads();

    // exclusive scan over 1024 bucket counts (wave scan + cross-wave offsets)
    int v = hist[t];
    int inc = v;
    for (int d = 1; d < 64; d <<= 1) {
        int u = __shfl_up(inc, d, 64);
        if (lane >= d) inc += u;
    }
    if (lane == 63) wsum[w] = inc;
    __syncthreads();
    int add = 0;
    for (int ww = 0; ww < w; ++ww) add += wsum[ww];
    wpos[t] = inc - v + add;                          // exclusive base within block
    gbase[t] = atomicAdd(&cursor[t * CSTRIDE], v);    // global base in bucket slab
    __syncthreads();

    // scatter into LDS, bucket-major
#pragma unroll
    for (int i = 0; i < 16; ++i) {
        int bkt = c[i] >> BSHIFT;
        int idx = atomicAdd(&wpos[bkt], 1);
        buf[idx] = ((unsigned int)r[i] << 8) | (unsigned int)(c[i] & (NODES_PER_BUCK - 1));
    }
    __syncthreads();

    // flush: each wave owns 64 buckets; one contiguous run per bucket
    for (int it = 0; it < 64; ++it) {
        int j = w * 64 + it;
        int cnt = hist[j];
        int src = wpos[j] - cnt;   // wpos now == base + cnt
        int dst0 = gbase[j];
        for (int k2 = lane; k2 < cnt; k2 += 64) {
            int d = dst0 + k2;
            if (d < CAP_NEW) pairs[(size_t)j * CAP_NEW + d] = buf[src + k2];
        }
    }
}

// ---------------- K_pool: tile + LDS atomicMax, 32-deep gather batches -------
// Block NBUCK = BN finalize (folds k3). Normal blocks: init 64 KB tile from own
// h16 slab (self-loop fused), 32-deep independent gathers + ds atomicMax, then
// write pooled keys into the block's own (dead) pairs slab — zero global
// atomics. All pairs reads complete (syncthreads) before the slab overwrite.
__global__ __launch_bounds__(1024) void k_pool_new(const unsigned int* __restrict__ pairs_,
                                                   const int* __restrict__ cursor,
                                                   const unsigned short* __restrict__ h16,
                                                   float* __restrict__ stats2,
                                                   unsigned short* __restrict__ pooled16,
                                                   const float* __restrict__ partials,
                                                   const float* __restrict__ gamma,
                                                   const float* __restrict__ beta,
                                                   float invN) {
    __shared__ unsigned int tile[NODES_PER_BUCK * 64];  // 64 KB
    int b = blockIdx.x;
    int t = threadIdx.x;

    if (b == NBUCK) {
        float* fred = (float*)tile;          // [8][128]
        float* tot = ((float*)tile) + 1024;  // [128]
        int c = t & 127;
        int g = t >> 7;
        float s = 0.f;
        for (int pb = g; pb < GEMM_BLOCKS; pb += 8) s += partials[(size_t)pb * 128 + c];
        fred[g * 128 + c] = s;
        __syncthreads();
        if (t < 128) {
            float v = 0.f;
#pragma unroll
            for (int g2 = 0; g2 < 8; ++g2) v += fred[g2 * 128 + t];
            tot[t] = v;
        }
        __syncthreads();
        if (t < 64) {
            float mean = tot[t] * invN;
            float var = tot[64 + t] * invN - mean * mean;
            float sc = gamma[t] * rsqrtf(var + BN_EPS);
            stats2[t] = sc;
            stats2[64 + t] = beta[t] - mean * sc;
        }
        return;
    }

    int lane = t & 63;
    int w = t >> 6;

    const unsigned int* src = (const unsigned int*)(h16 + (size_t)b * (NODES_PER_BUCK * 64));
#pragma unroll
    for (int k = 0; k < 8; ++k) {
        int i = t + k * 1024;
        unsigned int u = src[i];
        tile[2 * i] = u & 0xFFFFu;
        tile[2 * i + 1] = u >> 16;
    }
    __syncthreads();

    int cntE = min(cursor[b * CSTRIDE], CAP_NEW);
    int start = b * CAP_NEW;
    int end = start + cntE;
    int chunk = (cntE + 15) >> 4;
    int cs = start + w * chunk;
    int ce = min(cs + chunk, end);
    for (int j0 = cs; j0 < ce; j0 += 64) {
        int lim = min(64, ce - j0);
        unsigned int pk = (lane < lim) ? pairs_[j0 + lane] : 0u;
        int jj = 0;
        for (; jj + 32 <= lim; jj += 32) {
            unsigned int qv[32];
            unsigned int vv[32];
#pragma unroll
            for (int u = 0; u < 32; ++u)
                qv[u] = (unsigned int)__builtin_amdgcn_readlane((int)pk, jj + u);
#pragma unroll
            for (int u = 0; u < 32; ++u)
                vv[u] = (unsigned int)h16[(size_t)(qv[u] >> 8) * 64 + lane];
#pragma unroll
            for (int u = 0; u < 32; ++u)
                atomicMax(&tile[((qv[u] & 255u) << 6) + lane], vv[u]);
        }
        for (; jj + 8 <= lim; jj += 8) {
            unsigned int qv[8];
            unsigned int vv[8];
#pragma unroll
            for (int u = 0; u < 8; ++u)
                qv[u] = (unsigned int)__builtin_amdgcn_readlane((int)pk, jj + u);
#pragma unroll
            for (int u = 0; u < 8; ++u)
                vv[u] = (unsigned int)h16[(size_t)(qv[u] >> 8) * 64 + lane];
#pragma unroll
            for (int u = 0; u < 8; ++u)
                atomicMax(&tile[((qv[u] & 255u) << 6) + lane], vv[u]);
        }
        for (; jj < lim; ++jj) {
            unsigned int qq = (unsigned int)__builtin_amdgcn_readlane((int)pk, jj);
            unsigned int v = h16[(size_t)(qq >> 8) * 64 + lane];
            atomicMax(&tile[((qq & 255u) << 6) + lane], v);
        }
    }
    __syncthreads();  // all pairs reads done before slab overwrite

#pragma unroll
    for (int nl = 0; nl < NODES_PER_BUCK; nl += 16) {
        int node_l = nl + w;
        pooled16[((size_t)((b << BSHIFT) + node_l)) * 64 + lane] =
            (unsigned short)tile[(node_l << 6) + lane];
    }
}

// ---------------- K_vox: per-voxel gather-reduce, no atomics, fuses k7 -------
__global__ __launch_bounds__(256) void k_vox(const unsigned short* __restrict__ pooled16,
                                             const int* __restrict__ vlist,
                                             const int* __restrict__ vcursor,
                                             const float* __restrict__ pos,
                                             const float* __restrict__ stats2,
                                             float* __restrict__ out) {
    int v = blockIdx.x * 4 + (threadIdx.x >> 6);  // one wave per voxel
    int lane = threadIdx.x & 63;
    int cv = vcursor[v * VSTRIDE];
    int c = min(cv, VCAP);
    float scale = stats2[lane], shift = stats2[64 + lane];
    const int* lst = vlist + (size_t)v * VCAP;
    float s0 = 0.f, s1 = 0.f, s2 = 0.f, s3 = 0.f;
    int i = 0;
    for (; i + 4 <= c; i += 4) {
        int n0 = lst[i], n1 = lst[i + 1], n2 = lst[i + 2], n3 = lst[i + 3];
        float v0 = key2f(pooled16[(size_t)n0 * 64 + lane]);
        float v1 = key2f(pooled16[(size_t)n1 * 64 + lane]);
        float v2 = key2f(pooled16[(size_t)n2 * 64 + lane]);
        float v3 = key2f(pooled16[(size_t)n3 * 64 + lane]);
        s0 += fmaxf(fmaf(v0, scale, shift), 0.f);
        s1 += fmaxf(fmaf(v1, scale, shift), 0.f);
        s2 += fmaxf(fmaf(v2, scale, shift), 0.f);
        s3 += fmaxf(fmaf(v3, scale, shift), 0.f);
    }
    for (; i < c; ++i) {
        float v0 = key2f(pooled16[(size_t)lst[i] * 64 + lane]);
        s0 += fmaxf(fmaf(v0, scale, shift), 0.f);
    }
    float den = 1.f / fmaxf((float)cv, 1.f);
    out[(size_t)v * 67 + lane] = (s0 + s1 + s2 + s3) * den;
    if (lane < 3) {
        float p0 = 0.f, p1 = 0.f, p2 = 0.f, p3 = 0.f;
        int j = 0;
        for (; j + 4 <= c; j += 4) {
            p0 += pos[(size_t)lst[j] * 3 + lane];
            p1 += pos[(size_t)lst[j + 1] * 3 + lane];
            p2 += pos[(size_t)lst[j + 2] * 3 + lane];
            p3 += pos[(size_t)lst[j + 3] * 3 + lane];
        }
        for (; j < c; ++j) p0 += pos[(size_t)lst[j] * 3 + lane];
        out[(size_t)v * 67 + 64 + lane] = (p0 + p1 + p2 + p3) * den;
    }
}

// ================= fallback path (R2-verified) ===============================
__global__ __launch_bounds__(256) void k0_fused_old(const float* __restrict__ x,
                                                    const float* __restrict__ W,
                                                    const float* __restrict__ bias,
                                                    unsigned short* __restrict__ h16,
                                                    float* __restrict__ partials, int n16,
                                                    const int* __restrict__ rows,
                                                    const int* __restrict__ cols,
                                                    int* __restrict__ cursor,
                                                    unsigned int* __restrict__ pairs,
                                                    float4* __restrict__ zero_zone,
                                                    int zero_n4) {
    __shared__ float sW[4096];
    __shared__ float red[2][4][64];
    __shared__ int lh[NBUCK];
    __shared__ int lpos[NBUCK];
    int t = threadIdx.x;
    int bid = blockIdx.x;

    if (bid >= 2 * GEMM_BLOCKS) {
        int zb = bid - 2 * GEMM_BLOCKS;
        float4 z = {0.f, 0.f, 0.f, 0.f};
        for (int i = zb * 256 + t; i < zero_n4; i += XTRA_BLOCKS * 256) zero_zone[i] = z;
        return;
    }

    if (bid & 1) {
        int bb = bid >> 1;
        for (int j = t; j < NBUCK; j += 256) lh[j] = 0;
        __syncthreads();
        int base = bb * 4096 + t * 16;
        int r[16], c[16];
#pragma unroll
        for (int g4 = 0; g4 < 4; ++g4) {
            int e = base + g4 * 4;
            int4 r4 = *(const int4*)(rows + e);
            int4 c4 = *(const int4*)(cols + e);
            r[g4 * 4 + 0] = r4.x; c[g4 * 4 + 0] = c4.x;
            r[g4 * 4 + 1] = r4.y; c[g4 * 4 + 1] = c4.y;
            r[g4 * 4 + 2] = r4.z; c[g4 * 4 + 2] = c4.z;
            r[g4 * 4 + 3] = r4.w; c[g4 * 4 + 3] = c4.w;
        }
#pragma unroll
        for (int i = 0; i < 16; ++i) atomicAdd(&lh[c[i] >> BSHIFT], 1);
        __syncthreads();
        for (int j = t; j < NBUCK; j += 256) lpos[j] = atomicAdd(&cursor[j], lh[j]);
        __syncthreads();
#pragma unroll
        for (int i = 0; i < 16; ++i) {
            int bkt = c[i] >> BSHIFT;
            int idx = atomicAdd(&lpos[bkt], 1);
            if (idx < CAP_OLD)
                pairs[(size_t)bkt * CAP_OLD + idx] =
                    ((unsigned int)r[i] << 8) | (unsigned int)(c[i] & (NODES_PER_BUCK - 1));
        }
        return;
    }

    int gb = bid >> 1;
    for (int i = t; i < 4096; i += 256) sW[i] = W[i];
    __syncthreads();
    int lane = t & 63;
    int w = t >> 6;
    int l15 = lane & 15;
    int q = lane >> 4;

    f16x8 bf[4][2];
#pragma unroll
    for (int t4 = 0; t4 < 4; ++t4)
#pragma unroll
        for (int kb = 0; kb < 2; ++kb)
#pragma unroll
            for (int i = 0; i < 8; ++i)
                bf[t4][kb][i] = (_Float16)sW[(kb * 32 + q * 8 + i) * 64 + t4 * 16 + l15];
    float bv[4];
#pragma unroll
    for (int t4 = 0; t4 < 4; ++t4) bv[t4] = bias[t4 * 16 + l15];

    float s[4] = {0.f, 0.f, 0.f, 0.f}, s2[4] = {0.f, 0.f, 0.f, 0.f};

    for (int g = gb * 4 + w; g < n16; g += GEMM_BLOCKS * 4) {
        int row0 = g * 16;
        const float* xp = x + (size_t)(row0 + l15) * 64 + q * 8;
        float4 xa = *(const float4*)(xp);
        float4 xb = *(const float4*)(xp + 4);
        float4 xc = *(const float4*)(xp + 32);
        float4 xd = *(const float4*)(xp + 36);
        gemm_step(row0, pack8(xa, xb), pack8(xc, xd), bf, bv, s, s2, h16, l15, q);
    }

#pragma unroll
    for (int t4 = 0; t4 < 4; ++t4) {
        s[t4] += __shfl_xor(s[t4], 16, 64);
        s[t4] += __shfl_xor(s[t4], 32, 64);
        s2[t4] += __shfl_xor(s2[t4], 16, 64);
        s2[t4] += __shfl_xor(s2[t4], 32, 64);
    }
    if (lane < 16) {
#pragma unroll
        for (int t4 = 0; t4 < 4; ++t4) {
            red[0][w][t4 * 16 + lane] = s[t4];
            red[1][w][t4 * 16 + lane] = s2[t4];
        }
    }
    __syncthreads();
    if (t < 128) {
        int c = t & 63;
        int which = t >> 6;
        float v = red[which][0][c] + red[which][1][c] + red[which][2][c] + red[which][3][c];
        partials[(size_t)gb * 128 + which * 64 + c] = v;
    }
}

__global__ __launch_bounds__(1024) void k3_finalize(const float* __restrict__ partials,
                                                    const float* __restrict__ gamma,
                                                    const float* __restrict__ beta,
                                                    float* __restrict__ stats2, float invN) {
    __shared__ float red[8][128];
    __shared__ float tot[128];
    int t = threadIdx.x;
    int c = t & 127;
    int g = t >> 7;
    float s = 0.f;
    for (int b = g; b < GEMM_BLOCKS; b += 8) s += partials[(size_t)b * 128 + c];
    red[g][c] = s;
    __syncthreads();
    if (t < 128) {
        float v = 0.f;
#pragma unroll
        for (int g2 = 0; g2 < 8; ++g2) v += red[g2][t];
        tot[t] = v;
    }
    __syncthreads();
    if (t < 64) {
        float mean = tot[t] * invN;
        float var = tot[64 + t] * invN - mean * mean;
        float sc = gamma[t] * rsqrtf(var + BN_EPS);
        stats2[t] = sc;
        stats2[64 + t] = beta[t] - mean * sc;
    }
}

__global__ __launch_bounds__(1024) void k_pool_old(const unsigned int* __restrict__ pairs_,
                                                   const int* __restrict__ cursor,
                                                   const unsigned short* __restrict__ h16,
                                                   const float* __restrict__ pos,
                                                   const float* __restrict__ stats2,
                                                   float* __restrict__ xs,
                                                   float* __restrict__ ps,
                                                   float* __restrict__ cnt) {
    __shared__ unsigned int tile[NODES_PER_BUCK * 64];
    int b = blockIdx.x;
    int t = threadIdx.x;
    int lane = t & 63;
    int w = t >> 6;
    float scale = stats2[lane];
    float shift = stats2[64 + lane];

    const unsigned int* src = (const unsigned int*)(h16 + (size_t)b * (NODES_PER_BUCK * 64));
#pragma unroll
    for (int k = 0; k < 8; ++k) {
        int i = t + k * 1024;
        unsigned int u = src[i];
        tile[2 * i] = u & 0xFFFFu;
        tile[2 * i + 1] = u >> 16;
    }
    __syncthreads();

    int cntE = min(cursor[b], CAP_OLD);
    int start = b * CAP_OLD;
    int end = start + cntE;
    int chunk = (cntE + 15) >> 4;
    int cs = start + w * chunk;
    int ce = min(cs + chunk, end);
    for (int j0 = cs; j0 < ce; j0 += 64) {
        int lim = min(64, ce - j0);
        unsigned int pk = (lane < lim) ? pairs_[j0 + lane] : 0u;
        int jj = 0;
        for (; jj + 16 <= lim; jj += 16) {
            unsigned int qv[16];
            unsigned short vv[16];
#pragma unroll
            for (int u = 0; u < 16; ++u)
                qv[u] = (unsigned int)__builtin_amdgcn_readlane((int)pk, jj + u);
#pragma unroll
            for (int u = 0; u < 16; ++u) vv[u] = h16[(size_t)(qv[u] >> 8) * 64 + lane];
#pragma unroll
            for (int u = 0; u < 16; ++u)
                atomicMax(&tile[((qv[u] & 255u) << 6) + lane], (unsigned int)vv[u]);
        }
        for (; jj < lim; ++jj) {
            unsigned int qq = (unsigned int)__builtin_amdgcn_readlane((int)pk, jj);
            unsigned int v = h16[(size_t)(qq >> 8) * 64 + lane];
            atomicMax(&tile[((qq & 255u) << 6) + lane], v);
        }
    }
    __syncthreads();

#pragma unroll
    for (int nl = 0; nl < NODES_PER_BUCK; nl += 16) {
        int node_l = nl + w;
        int c = (b << BSHIFT) + node_l;
        float px = pos[(size_t)c * 3 + 0];
        float py = pos[(size_t)c * 3 + 1];
        float pz = pos[(size_t)c * 3 + 2];
        int v0 = min(max((int)floorf(px * 2.f), 0), NVOX_DIM - 1);
        int v1 = min(max((int)floorf(py * 2.f), 0), NVOX_DIM - 1);
        int v2 = min(max((int)floorf(pz * 2.f), 0), NVOX_DIM - 1);
        int vox = (v0 * NVOX_DIM + v1) * NVOX_DIM + v2;
        float v = key2f(tile[(node_l << 6) + lane]);
        float val = fmaxf(fmaf(v, scale, shift), 0.f);
        atomicAdd(&xs[(size_t)vox * 64 + lane], val);
        if (lane < 3) atomicAdd(&ps[vox * 3 + lane], lane == 0 ? px : (lane == 1 ? py : pz));
        if (lane == 0) atomicAdd(&cnt[vox], 1.f);
    }
}

__global__ __launch_bounds__(256) void k7_out(const float* __restrict__ xs,
                                              const float* __restrict__ ps,
                                              const float* __restrict__ cnt,
                                              float* __restrict__ out, int total) {
    int idx = blockIdx.x * blockDim.x + threadIdx.x;
    if (idx >= total) return;
    int v = idx / 67;
    int c = idx - v * 67;
    float d = fmaxf(cnt[v], 1.f);
    float val = (c < 64) ? xs[(size_t)v * 64 + c] : ps[v * 3 + (c - 64)];
    out[idx] = val / d;
}

extern "C" void kernel_launch(void* const* d_in, const int* in_sizes, int n_in,
                              void* d_out, int out_size, void* d_ws, size_t ws_size,
                              hipStream_t stream) {
    const float* x     = (const float*)d_in[0];
    const float* pos   = (const float*)d_in[1];
    const int*   ei    = (const int*)d_in[2];
    const float* W     = (const float*)d_in[3];
    const float* b     = (const float*)d_in[4];
    const float* gamma = (const float*)d_in[5];
    const float* beta  = (const float*)d_in[6];
    float* out = (float*)d_out;

    const int n = in_sizes[0] / 64;   // 262144
    const int E = in_sizes[2] / 2;    // 4194304
    char* ws = (char*)d_ws;

    const size_t NEED_NEW = 70643712;
    if (ws_size >= NEED_NEW) {
        // New layout (bytes):
        //   h16      @ 0          : 33,554,432
        //   pairs    @ 33,554,432 : 33,554,432  (1024 x 8192 u32; reused as pooled16)
        //   partials @ 67,108,864 : 524,288
        //   stats2   @ 67,633,152 : 1,024
        //   cursor   @ 67,634,176 : 65,536      (1024 x 16-int line-padded)
        //   vcursor  @ 67,699,712 : 128,000     (8000 x 4-int padded)
        //   vlist    @ 67,827,712 : 2,816,000   -> end 70,643,712
        unsigned short* h16      = (unsigned short*)(ws + 0);
        unsigned int*   pairs    = (unsigned int*)(ws + 33554432);
        unsigned short* pooled16 = (unsigned short*)(ws + 33554432);
        float*          partials = (float*)(ws + 67108864);
        float*          stats2   = (float*)(ws + 67633152);
        int*            cursor   = (int*)(ws + 67634176);
        int*            vcursor  = (int*)(ws + 67699712);
        int*            vlist    = (int*)(ws + 67827712);

        k_zero<<<189, 256, 0, stream>>>(cursor, 48384);  // cursor + vcursor contiguous
        k0_gemm<<<GEMM_BLOCKS + XTRA_BLOCKS, 256, 0, stream>>>(
            x, W, b, h16, partials, n >> 4, pos, vcursor, vlist);
        k_bin2<<<E / BIN_EPB, 1024, 0, stream>>>(ei, ei + E, cursor, pairs);
        k_pool_new<<<NBUCK + 1, 1024, 0, stream>>>(pairs, cursor, h16, stats2, pooled16,
                                                   partials, gamma, beta, 1.0f / (float)n);
        k_vox<<<NVOX / 4, 256, 0, stream>>>(pooled16, vlist, vcursor, pos, stats2, out);
    } else {
        // Fallback: R2-verified layout/path
        unsigned short* h16      = (unsigned short*)(ws + 0);
        unsigned int*   pairs    = (unsigned int*)(ws + 33554432);
        float*          partials = (float*)(ws + 54525952);
        float*          stats2   = (float*)(ws + 55050240);
        int*            cursor   = (int*)(ws + 55051264);
        float*          xs       = (float*)(ws + 55055360);
        float*          ps       = (float*)(ws + 57103360);
        float*          cnt      = (float*)(ws + 57199360);
        float4*         zero4    = (float4*)(ws + 55055360);
        const int zero_n4 = (57231360 - 55055360) / 16;

        k_zero<<<4, 256, 0, stream>>>(cursor, NBUCK);
        k0_fused_old<<<2 * GEMM_BLOCKS + XTRA_BLOCKS, 256, 0, stream>>>(
            x, W, b, h16, partials, n >> 4, ei, ei + E, cursor, pairs, zero4, zero_n4);
        k3_finalize<<<1, 1024, 0, stream>>>(partials, gamma, beta, stats2, 1.0f / (float)n);
        k_pool_old<<<NBUCK, 1024, 0, stream>>>(pairs, cursor, h16, pos, stats2, xs, ps, cnt);
        k7_out<<<(out_size + 255) / 256, 256, 0, stream>>>(xs, ps, cnt, out, out_size);
    }
}

// Round 8
// 311.466 us; speedup vs baseline: 1.1130x; 1.1130x over previous
//
#include <hip/hip_runtime.h>
#include <hip/hip_fp16.h>

#define NVOX_DIM 20
#define NVOX 8000
#define BN_EPS 1e-5f

#define NBUCK 1024        // buckets = col >> 8
#define BSHIFT 8
#define NODES_PER_BUCK 256
#define GEMM_BLOCKS 1024
#define XTRA_BLOCKS 64
#define CAP_NEW 8192      // slab slots/bucket (32 KB) -> reused as pooled u16 rows
#define CAP_OLD 5120
#define VCAP 88           // nodes/voxel capacity: mean 32.8, sigma 5.7, exp-max ~57
#define CSTRIDE 16        // cursor padding: one 64B line per bucket counter
#define VSTRIDE 4         // vcursor padding: 16B per voxel counter
#define BIN_EPB 16384     // edges per k_bin2 block

typedef _Float16 f16x8 __attribute__((ext_vector_type(8)));
typedef float f32x4 __attribute__((ext_vector_type(4)));

// order-preserving u16 key for half bits: neg -> ~b, pos -> b|0x8000
__device__ __forceinline__ unsigned short f2key(float v) {
    unsigned short hb = __half_as_ushort(__float2half(v));
    unsigned short m = (unsigned short)(0x8000u | (unsigned short)(-(int)(hb >> 15)));
    return (unsigned short)(hb ^ m);
}

__device__ __forceinline__ float key2f(unsigned int k) {
    unsigned short hb = (k & 0x8000u) ? (unsigned short)(k ^ 0x8000u)
                                      : (unsigned short)(0xFFFFu ^ k);
    __half_raw hr;
    hr.x = hb;
    return __half2float((__half)hr);
}

__device__ __forceinline__ f16x8 pack8(float4 a, float4 b) {
    f16x8 r;
    r[0] = (_Float16)a.x; r[1] = (_Float16)a.y; r[2] = (_Float16)a.z; r[3] = (_Float16)a.w;
    r[4] = (_Float16)b.x; r[5] = (_Float16)b.y; r[6] = (_Float16)b.z; r[7] = (_Float16)b.w;
    return r;
}

// one 16-row group (fallback path): 8 MFMAs + stats + scattered u16-key stores
__device__ __forceinline__ void gemm_step(int row0, f16x8 a0, f16x8 a1,
                                          const f16x8 (&bf)[4][2], const float (&bv)[4],
                                          float (&s)[4], float (&s2)[4],
                                          unsigned short* __restrict__ h16,
                                          int l15, int q) {
#pragma unroll
    for (int t4 = 0; t4 < 4; ++t4) {
        f32x4 acc = {bv[t4], bv[t4], bv[t4], bv[t4]};
        acc = __builtin_amdgcn_mfma_f32_16x16x32_f16(a0, bf[t4][0], acc, 0, 0, 0);
        acc = __builtin_amdgcn_mfma_f32_16x16x32_f16(a1, bf[t4][1], acc, 0, 0, 0);
        s[t4] += acc[0] + acc[1] + acc[2] + acc[3];
        s2[t4] = fmaf(acc[0], acc[0], s2[t4]);
        s2[t4] = fmaf(acc[1], acc[1], s2[t4]);
        s2[t4] = fmaf(acc[2], acc[2], s2[t4]);
        s2[t4] = fmaf(acc[3], acc[3], s2[t4]);
#pragma unroll
        for (int r = 0; r < 4; ++r) {
            h16[(size_t)(row0 + q * 4 + r) * 64 + t4 * 16 + l15] = f2key(acc[r]);
        }
    }
}

// ---------------- K-1: zero an int region (cursors) --------------------------
__global__ __launch_bounds__(256) void k_zero(int* __restrict__ p, int n) {
    int i = blockIdx.x * 256 + threadIdx.x;
    if (i < n) p[i] = 0;
}

// ---------------- K0 (NEW): GEMM + stats | node->voxel binning ---------------
// 512-thread blocks (8 waves): TLP fix for the latency-bound x-read stream
// (R4/R6 measured 25% occupancy, 0.5-1 TB/s; ILP-unroll regressed in R7).
// h16 epilogue is LDS-staged per wave ([16][65] u16, conflict-free, same-wave
// so no barrier) then flushed as 16 fully-coalesced 128-B row stores — kills
// the measured 3.5x write amplification of the scattered 2-B store pattern.
__global__ __launch_bounds__(512) void k0_gemm(const float* __restrict__ x,
                                               const float* __restrict__ W,
                                               const float* __restrict__ bias,
                                               unsigned short* __restrict__ h16,
                                               float* __restrict__ partials, int n16,
                                               const float* __restrict__ pos,
                                               int* __restrict__ vcursor,
                                               int* __restrict__ vlist) {
    __shared__ float sW[4096];
    __shared__ float red[2][8][64];
    __shared__ unsigned short stg[8][16][65];
    int t = threadIdx.x;
    int bid = blockIdx.x;

    if (bid >= GEMM_BLOCKS) {
        int zb = bid - GEMM_BLOCKS;
        int nNodes = n16 * 16;
        for (int nd = zb * 512 + t; nd < nNodes; nd += XTRA_BLOCKS * 512) {
            float px = pos[(size_t)nd * 3 + 0];
            float py = pos[(size_t)nd * 3 + 1];
            float pz = pos[(size_t)nd * 3 + 2];
            int v0 = min(max((int)floorf(px * 2.f), 0), NVOX_DIM - 1);
            int v1 = min(max((int)floorf(py * 2.f), 0), NVOX_DIM - 1);
            int v2 = min(max((int)floorf(pz * 2.f), 0), NVOX_DIM - 1);
            int vox = (v0 * NVOX_DIM + v1) * NVOX_DIM + v2;
            int idx = atomicAdd(&vcursor[vox * VSTRIDE], 1);
            if (idx < VCAP) vlist[vox * VCAP + idx] = nd;
        }
        return;
    }

    int gb = bid;
    for (int i = t; i < 4096; i += 512) sW[i] = W[i];
    __syncthreads();
    int lane = t & 63;
    int w = t >> 6;  // wave 0..7
    int l15 = lane & 15;
    int q = lane >> 4;

    f16x8 bf[4][2];
#pragma unroll
    for (int t4 = 0; t4 < 4; ++t4)
#pragma unroll
        for (int kb = 0; kb < 2; ++kb)
#pragma unroll
            for (int i = 0; i < 8; ++i)
                bf[t4][kb][i] = (_Float16)sW[(kb * 32 + q * 8 + i) * 64 + t4 * 16 + l15];
    float bv[4];
#pragma unroll
    for (int t4 = 0; t4 < 4; ++t4) bv[t4] = bias[t4 * 16 + l15];

    float s[4] = {0.f, 0.f, 0.f, 0.f}, s2[4] = {0.f, 0.f, 0.f, 0.f};

    for (int g = gb * 8 + w; g < n16; g += GEMM_BLOCKS * 8) {
        int row0 = g * 16;
        const float* xp = x + (size_t)(row0 + l15) * 64 + q * 8;
        float4 xa = *(const float4*)(xp);
        float4 xb = *(const float4*)(xp + 4);
        float4 xc = *(const float4*)(xp + 32);
        float4 xd = *(const float4*)(xp + 36);
        f16x8 a0 = pack8(xa, xb), a1 = pack8(xc, xd);

#pragma unroll
        for (int t4 = 0; t4 < 4; ++t4) {
            f32x4 acc = {bv[t4], bv[t4], bv[t4], bv[t4]};
            acc = __builtin_amdgcn_mfma_f32_16x16x32_f16(a0, bf[t4][0], acc, 0, 0, 0);
            acc = __builtin_amdgcn_mfma_f32_16x16x32_f16(a1, bf[t4][1], acc, 0, 0, 0);
            s[t4] += acc[0] + acc[1] + acc[2] + acc[3];
            s2[t4] = fmaf(acc[0], acc[0], s2[t4]);
            s2[t4] = fmaf(acc[1], acc[1], s2[t4]);
            s2[t4] = fmaf(acc[2], acc[2], s2[t4]);
            s2[t4] = fmaf(acc[3], acc[3], s2[t4]);
#pragma unroll
            for (int r = 0; r < 4; ++r)
                stg[w][q * 4 + r][t4 * 16 + l15] = f2key(acc[r]);
        }
        // flush: 16 coalesced 128-B row stores (same-wave LDS transpose,
        // compiler inserts the lgkmcnt wait; no barrier needed)
#pragma unroll
        for (int i = 0; i < 16; ++i)
            h16[(size_t)(row0 + i) * 64 + lane] = stg[w][i][lane];
    }

#pragma unroll
    for (int t4 = 0; t4 < 4; ++t4) {
        s[t4] += __shfl_xor(s[t4], 16, 64);
        s[t4] += __shfl_xor(s[t4], 32, 64);
        s2[t4] += __shfl_xor(s2[t4], 16, 64);
        s2[t4] += __shfl_xor(s2[t4], 32, 64);
    }
    if (lane < 16) {
#pragma unroll
        for (int t4 = 0; t4 < 4; ++t4) {
            red[0][w][t4 * 16 + lane] = s[t4];
            red[1][w][t4 * 16 + lane] = s2[t4];
        }
    }
    __syncthreads();
    if (t < 128) {
        int c = t & 63;
        int which = t >> 6;
        float v = 0.f;
#pragma unroll
        for (int ww = 0; ww < 8; ++ww) v += red[which][ww][c];
        partials[(size_t)gb * 128 + which * 64 + c] = v;
    }
}

// ---------------- K_bin2: full in-LDS partition, coalesced flush -------------
__global__ __launch_bounds__(1024) void k_bin2(const int* __restrict__ rows,
                                               const int* __restrict__ cols,
                                               int* __restrict__ cursor,
                                               unsigned int* __restrict__ pairs) {
    __shared__ unsigned int buf[BIN_EPB];  // 64 KB
    __shared__ int hist[NBUCK];
    __shared__ int wpos[NBUCK];
    __shared__ int gbase[NBUCK];
    __shared__ int wsum[16];
    int t = threadIdx.x;
    int lane = t & 63;
    int w = t >> 6;

    hist[t] = 0;
    __syncthreads();

    int base_e = blockIdx.x * BIN_EPB + t * 16;
    int r[16], c[16];
#pragma unroll
    for (int g4 = 0; g4 < 4; ++g4) {
        int e = base_e + g4 * 4;
        int4 r4 = *(const int4*)(rows + e);
        int4 c4 = *(const int4*)(cols + e);
        r[g4 * 4 + 0] = r4.x; c[g4 * 4 + 0] = c4.x;
        r[g4 * 4 + 1] = r4.y; c[g4 * 4 + 1] = c4.y;
        r[g4 * 4 + 2] = r4.z; c[g4 * 4 + 2] = c4.z;
        r[g4 * 4 + 3] = r4.w; c[g4 * 4 + 3] = c4.w;
    }
#pragma unroll
    for (int i = 0; i < 16; ++i) atomicAdd(&hist[c[i] >> BSHIFT], 1);
    __syncthreads();

    // exclusive scan over 1024 bucket counts (wave scan + cross-wave offsets)
    int v = hist[t];
    int inc = v;
    for (int d = 1; d < 64; d <<= 1) {
        int u = __shfl_up(inc, d, 64);
        if (lane >= d) inc += u;
    }
    if (lane == 63) wsum[w] = inc;
    __syncthreads();
    int add = 0;
    for (int ww = 0; ww < w; ++ww) add += wsum[ww];
    wpos[t] = inc - v + add;                          // exclusive base within block
    gbase[t] = atomicAdd(&cursor[t * CSTRIDE], v);    // global base in bucket slab
    __syncthreads();

    // scatter into LDS, bucket-major
#pragma unroll
    for (int i = 0; i < 16; ++i) {
        int bkt = c[i] >> BSHIFT;
        int idx = atomicAdd(&wpos[bkt], 1);
        buf[idx] = ((unsigned int)r[i] << 8) | (unsigned int)(c[i] & (NODES_PER_BUCK - 1));
    }
    __syncthreads();

    // flush: each wave owns 64 buckets; one contiguous run per bucket
    for (int it = 0; it < 64; ++it) {
        int j = w * 64 + it;
        int cnt = hist[j];
        int src = wpos[j] - cnt;   // wpos now == base + cnt
        int dst0 = gbase[j];
        for (int k2 = lane; k2 < cnt; k2 += 64) {
            int d = dst0 + k2;
            if (d < CAP_NEW) pairs[(size_t)j * CAP_NEW + d] = buf[src + k2];
        }
    }
}

// ---------------- K_pool: tile + LDS atomicMax, 32-deep gather batches -------
__global__ __launch_bounds__(1024) void k_pool_new(const unsigned int* __restrict__ pairs_,
                                                   const int* __restrict__ cursor,
                                                   const unsigned short* __restrict__ h16,
                                                   float* __restrict__ stats2,
                                                   unsigned short* __restrict__ pooled16,
                                                   const float* __restrict__ partials,
                                                   const float* __restrict__ gamma,
                                                   const float* __restrict__ beta,
                                                   float invN) {
    __shared__ unsigned int tile[NODES_PER_BUCK * 64];  // 64 KB
    int b = blockIdx.x;
    int t = threadIdx.x;

    if (b == NBUCK) {
        float* fred = (float*)tile;          // [8][128]
        float* tot = ((float*)tile) + 1024;  // [128]
        int c = t & 127;
        int g = t >> 7;
        float s = 0.f;
        for (int pb = g; pb < GEMM_BLOCKS; pb += 8) s += partials[(size_t)pb * 128 + c];
        fred[g * 128 + c] = s;
        __syncthreads();
        if (t < 128) {
            float v = 0.f;
#pragma unroll
            for (int g2 = 0; g2 < 8; ++g2) v += fred[g2 * 128 + t];
            tot[t] = v;
        }
        __syncthreads();
        if (t < 64) {
            float mean = tot[t] * invN;
            float var = tot[64 + t] * invN - mean * mean;
            float sc = gamma[t] * rsqrtf(var + BN_EPS);
            stats2[t] = sc;
            stats2[64 + t] = beta[t] - mean * sc;
        }
        return;
    }

    int lane = t & 63;
    int w = t >> 6;

    const unsigned int* src = (const unsigned int*)(h16 + (size_t)b * (NODES_PER_BUCK * 64));
#pragma unroll
    for (int k = 0; k < 8; ++k) {
        int i = t + k * 1024;
        unsigned int u = src[i];
        tile[2 * i] = u & 0xFFFFu;
        tile[2 * i + 1] = u >> 16;
    }
    __syncthreads();

    int cntE = min(cursor[b * CSTRIDE], CAP_NEW);
    int start = b * CAP_NEW;
    int end = start + cntE;
    int chunk = (cntE + 15) >> 4;
    int cs = start + w * chunk;
    int ce = min(cs + chunk, end);
    for (int j0 = cs; j0 < ce; j0 += 64) {
        int lim = min(64, ce - j0);
        unsigned int pk = (lane < lim) ? pairs_[j0 + lane] : 0u;
        int jj = 0;
        for (; jj + 32 <= lim; jj += 32) {
            unsigned int qv[32];
            unsigned int vv[32];
#pragma unroll
            for (int u = 0; u < 32; ++u)
                qv[u] = (unsigned int)__builtin_amdgcn_readlane((int)pk, jj + u);
#pragma unroll
            for (int u = 0; u < 32; ++u)
                vv[u] = (unsigned int)h16[(size_t)(qv[u] >> 8) * 64 + lane];
#pragma unroll
            for (int u = 0; u < 32; ++u)
                atomicMax(&tile[((qv[u] & 255u) << 6) + lane], vv[u]);
        }
        for (; jj + 8 <= lim; jj += 8) {
            unsigned int qv[8];
            unsigned int vv[8];
#pragma unroll
            for (int u = 0; u < 8; ++u)
                qv[u] = (unsigned int)__builtin_amdgcn_readlane((int)pk, jj + u);
#pragma unroll
            for (int u = 0; u < 8; ++u)
                vv[u] = (unsigned int)h16[(size_t)(qv[u] >> 8) * 64 + lane];
#pragma unroll
            for (int u = 0; u < 8; ++u)
                atomicMax(&tile[((qv[u] & 255u) << 6) + lane], vv[u]);
        }
        for (; jj < lim; ++jj) {
            unsigned int qq = (unsigned int)__builtin_amdgcn_readlane((int)pk, jj);
            unsigned int v = h16[(size_t)(qq >> 8) * 64 + lane];
            atomicMax(&tile[((qq & 255u) << 6) + lane], v);
        }
    }
    __syncthreads();  // all pairs reads done before slab overwrite

#pragma unroll
    for (int nl = 0; nl < NODES_PER_BUCK; nl += 16) {
        int node_l = nl + w;
        pooled16[((size_t)((b << BSHIFT) + node_l)) * 64 + lane] =
            (unsigned short)tile[(node_l << 6) + lane];
    }
}

// ---------------- K_vox: per-voxel gather-reduce, no atomics, fuses k7 -------
__global__ __launch_bounds__(256) void k_vox(const unsigned short* __restrict__ pooled16,
                                             const int* __restrict__ vlist,
                                             const int* __restrict__ vcursor,
                                             const float* __restrict__ pos,
                                             const float* __restrict__ stats2,
                                             float* __restrict__ out) {
    int v = blockIdx.x * 4 + (threadIdx.x >> 6);  // one wave per voxel
    int lane = threadIdx.x & 63;
    int cv = vcursor[v * VSTRIDE];
    int c = min(cv, VCAP);
    float scale = stats2[lane], shift = stats2[64 + lane];
    const int* lst = vlist + (size_t)v * VCAP;
    float s0 = 0.f, s1 = 0.f, s2 = 0.f, s3 = 0.f;
    int i = 0;
    for (; i + 4 <= c; i += 4) {
        int n0 = lst[i], n1 = lst[i + 1], n2 = lst[i + 2], n3 = lst[i + 3];
        float v0 = key2f(pooled16[(size_t)n0 * 64 + lane]);
        float v1 = key2f(pooled16[(size_t)n1 * 64 + lane]);
        float v2 = key2f(pooled16[(size_t)n2 * 64 + lane]);
        float v3 = key2f(pooled16[(size_t)n3 * 64 + lane]);
        s0 += fmaxf(fmaf(v0, scale, shift), 0.f);
        s1 += fmaxf(fmaf(v1, scale, shift), 0.f);
        s2 += fmaxf(fmaf(v2, scale, shift), 0.f);
        s3 += fmaxf(fmaf(v3, scale, shift), 0.f);
    }
    for (; i < c; ++i) {
        float v0 = key2f(pooled16[(size_t)lst[i] * 64 + lane]);
        s0 += fmaxf(fmaf(v0, scale, shift), 0.f);
    }
    float den = 1.f / fmaxf((float)cv, 1.f);
    out[(size_t)v * 67 + lane] = (s0 + s1 + s2 + s3) * den;
    if (lane < 3) {
        float p0 = 0.f, p1 = 0.f, p2 = 0.f, p3 = 0.f;
        int j = 0;
        for (; j + 4 <= c; j += 4) {
            p0 += pos[(size_t)lst[j] * 3 + lane];
            p1 += pos[(size_t)lst[j + 1] * 3 + lane];
            p2 += pos[(size_t)lst[j + 2] * 3 + lane];
            p3 += pos[(size_t)lst[j + 3] * 3 + lane];
        }
        for (; j < c; ++j) p0 += pos[(size_t)lst[j] * 3 + lane];
        out[(size_t)v * 67 + 64 + lane] = (p0 + p1 + p2 + p3) * den;
    }
}

// ================= fallback path (R2-verified) ===============================
__global__ __launch_bounds__(256) void k0_fused_old(const float* __restrict__ x,
                                                    const float* __restrict__ W,
                                                    const float* __restrict__ bias,
                                                    unsigned short* __restrict__ h16,
                                                    float* __restrict__ partials, int n16,
                                                    const int* __restrict__ rows,
                                                    const int* __restrict__ cols,
                                                    int* __restrict__ cursor,
                                                    unsigned int* __restrict__ pairs,
                                                    float4* __restrict__ zero_zone,
                                                    int zero_n4) {
    __shared__ float sW[4096];
    __shared__ float red[2][4][64];
    __shared__ int lh[NBUCK];
    __shared__ int lpos[NBUCK];
    int t = threadIdx.x;
    int bid = blockIdx.x;

    if (bid >= 2 * GEMM_BLOCKS) {
        int zb = bid - 2 * GEMM_BLOCKS;
        float4 z = {0.f, 0.f, 0.f, 0.f};
        for (int i = zb * 256 + t; i < zero_n4; i += XTRA_BLOCKS * 256) zero_zone[i] = z;
        return;
    }

    if (bid & 1) {
        int bb = bid >> 1;
        for (int j = t; j < NBUCK; j += 256) lh[j] = 0;
        __syncthreads();
        int base = bb * 4096 + t * 16;
        int r[16], c[16];
#pragma unroll
        for (int g4 = 0; g4 < 4; ++g4) {
            int e = base + g4 * 4;
            int4 r4 = *(const int4*)(rows + e);
            int4 c4 = *(const int4*)(cols + e);
            r[g4 * 4 + 0] = r4.x; c[g4 * 4 + 0] = c4.x;
            r[g4 * 4 + 1] = r4.y; c[g4 * 4 + 1] = c4.y;
            r[g4 * 4 + 2] = r4.z; c[g4 * 4 + 2] = c4.z;
            r[g4 * 4 + 3] = r4.w; c[g4 * 4 + 3] = c4.w;
        }
#pragma unroll
        for (int i = 0; i < 16; ++i) atomicAdd(&lh[c[i] >> BSHIFT], 1);
        __syncthreads();
        for (int j = t; j < NBUCK; j += 256) lpos[j] = atomicAdd(&cursor[j], lh[j]);
        __syncthreads();
#pragma unroll
        for (int i = 0; i < 16; ++i) {
            int bkt = c[i] >> BSHIFT;
            int idx = atomicAdd(&lpos[bkt], 1);
            if (idx < CAP_OLD)
                pairs[(size_t)bkt * CAP_OLD + idx] =
                    ((unsigned int)r[i] << 8) | (unsigned int)(c[i] & (NODES_PER_BUCK - 1));
        }
        return;
    }

    int gb = bid >> 1;
    for (int i = t; i < 4096; i += 256) sW[i] = W[i];
    __syncthreads();
    int lane = t & 63;
    int w = t >> 6;
    int l15 = lane & 15;
    int q = lane >> 4;

    f16x8 bf[4][2];
#pragma unroll
    for (int t4 = 0; t4 < 4; ++t4)
#pragma unroll
        for (int kb = 0; kb < 2; ++kb)
#pragma unroll
            for (int i = 0; i < 8; ++i)
                bf[t4][kb][i] = (_Float16)sW[(kb * 32 + q * 8 + i) * 64 + t4 * 16 + l15];
    float bv[4];
#pragma unroll
    for (int t4 = 0; t4 < 4; ++t4) bv[t4] = bias[t4 * 16 + l15];

    float s[4] = {0.f, 0.f, 0.f, 0.f}, s2[4] = {0.f, 0.f, 0.f, 0.f};

    for (int g = gb * 4 + w; g < n16; g += GEMM_BLOCKS * 4) {
        int row0 = g * 16;
        const float* xp = x + (size_t)(row0 + l15) * 64 + q * 8;
        float4 xa = *(const float4*)(xp);
        float4 xb = *(const float4*)(xp + 4);
        float4 xc = *(const float4*)(xp + 32);
        float4 xd = *(const float4*)(xp + 36);
        gemm_step(row0, pack8(xa, xb), pack8(xc, xd), bf, bv, s, s2, h16, l15, q);
    }

#pragma unroll
    for (int t4 = 0; t4 < 4; ++t4) {
        s[t4] += __shfl_xor(s[t4], 16, 64);
        s[t4] += __shfl_xor(s[t4], 32, 64);
        s2[t4] += __shfl_xor(s2[t4], 16, 64);
        s2[t4] += __shfl_xor(s2[t4], 32, 64);
    }
    if (lane < 16) {
#pragma unroll
        for (int t4 = 0; t4 < 4; ++t4) {
            red[0][w][t4 * 16 + lane] = s[t4];
            red[1][w][t4 * 16 + lane] = s2[t4];
        }
    }
    __syncthreads();
    if (t < 128) {
        int c = t & 63;
        int which = t >> 6;
        float v = red[which][0][c] + red[which][1][c] + red[which][2][c] + red[which][3][c];
        partials[(size_t)gb * 128 + which * 64 + c] = v;
    }
}

__global__ __launch_bounds__(1024) void k3_finalize(const float* __restrict__ partials,
                                                    const float* __restrict__ gamma,
                                                    const float* __restrict__ beta,
                                                    float* __restrict__ stats2, float invN) {
    __shared__ float red[8][128];
    __shared__ float tot[128];
    int t = threadIdx.x;
    int c = t & 127;
    int g = t >> 7;
    float s = 0.f;
    for (int b = g; b < GEMM_BLOCKS; b += 8) s += partials[(size_t)b * 128 + c];
    red[g][c] = s;
    __syncthreads();
    if (t < 128) {
        float v = 0.f;
#pragma unroll
        for (int g2 = 0; g2 < 8; ++g2) v += red[g2][t];
        tot[t] = v;
    }
    __syncthreads();
    if (t < 64) {
        float mean = tot[t] * invN;
        float var = tot[64 + t] * invN - mean * mean;
        float sc = gamma[t] * rsqrtf(var + BN_EPS);
        stats2[t] = sc;
        stats2[64 + t] = beta[t] - mean * sc;
    }
}

__global__ __launch_bounds__(1024) void k_pool_old(const unsigned int* __restrict__ pairs_,
                                                   const int* __restrict__ cursor,
                                                   const unsigned short* __restrict__ h16,
                                                   const float* __restrict__ pos,
                                                   const float* __restrict__ stats2,
                                                   float* __restrict__ xs,
                                                   float* __restrict__ ps,
                                                   float* __restrict__ cnt) {
    __shared__ unsigned int tile[NODES_PER_BUCK * 64];
    int b = blockIdx.x;
    int t = threadIdx.x;
    int lane = t & 63;
    int w = t >> 6;
    float scale = stats2[lane];
    float shift = stats2[64 + lane];

    const unsigned int* src = (const unsigned int*)(h16 + (size_t)b * (NODES_PER_BUCK * 64));
#pragma unroll
    for (int k = 0; k < 8; ++k) {
        int i = t + k * 1024;
        unsigned int u = src[i];
        tile[2 * i] = u & 0xFFFFu;
        tile[2 * i + 1] = u >> 16;
    }
    __syncthreads();

    int cntE = min(cursor[b], CAP_OLD);
    int start = b * CAP_OLD;
    int end = start + cntE;
    int chunk = (cntE + 15) >> 4;
    int cs = start + w * chunk;
    int ce = min(cs + chunk, end);
    for (int j0 = cs; j0 < ce; j0 += 64) {
        int lim = min(64, ce - j0);
        unsigned int pk = (lane < lim) ? pairs_[j0 + lane] : 0u;
        int jj = 0;
        for (; jj + 16 <= lim; jj += 16) {
            unsigned int qv[16];
            unsigned short vv[16];
#pragma unroll
            for (int u = 0; u < 16; ++u)
                qv[u] = (unsigned int)__builtin_amdgcn_readlane((int)pk, jj + u);
#pragma unroll
            for (int u = 0; u < 16; ++u) vv[u] = h16[(size_t)(qv[u] >> 8) * 64 + lane];
#pragma unroll
            for (int u = 0; u < 16; ++u)
                atomicMax(&tile[((qv[u] & 255u) << 6) + lane], (unsigned int)vv[u]);
        }
        for (; jj < lim; ++jj) {
            unsigned int qq = (unsigned int)__builtin_amdgcn_readlane((int)pk, jj);
            unsigned int v = h16[(size_t)(qq >> 8) * 64 + lane];
            atomicMax(&tile[((qq & 255u) << 6) + lane], v);
        }
    }
    __syncthreads();

#pragma unroll
    for (int nl = 0; nl < NODES_PER_BUCK; nl += 16) {
        int node_l = nl + w;
        int c = (b << BSHIFT) + node_l;
        float px = pos[(size_t)c * 3 + 0];
        float py = pos[(size_t)c * 3 + 1];
        float pz = pos[(size_t)c * 3 + 2];
        int v0 = min(max((int)floorf(px * 2.f), 0), NVOX_DIM - 1);
        int v1 = min(max((int)floorf(py * 2.f), 0), NVOX_DIM - 1);
        int v2 = min(max((int)floorf(pz * 2.f), 0), NVOX_DIM - 1);
        int vox = (v0 * NVOX_DIM + v1) * NVOX_DIM + v2;
        float v = key2f(tile[(node_l << 6) + lane]);
        float val = fmaxf(fmaf(v, scale, shift), 0.f);
        atomicAdd(&xs[(size_t)vox * 64 + lane], val);
        if (lane < 3) atomicAdd(&ps[vox * 3 + lane], lane == 0 ? px : (lane == 1 ? py : pz));
        if (lane == 0) atomicAdd(&cnt[vox], 1.f);
    }
}

__global__ __launch_bounds__(256) void k7_out(const float* __restrict__ xs,
                                              const float* __restrict__ ps,
                                              const float* __restrict__ cnt,
                                              float* __restrict__ out, int total) {
    int idx = blockIdx.x * blockDim.x + threadIdx.x;
    if (idx >= total) return;
    int v = idx / 67;
    int c = idx - v * 67;
    float d = fmaxf(cnt[v], 1.f);
    float val = (c < 64) ? xs[(size_t)v * 64 + c] : ps[v * 3 + (c - 64)];
    out[idx] = val / d;
}

extern "C" void kernel_launch(void* const* d_in, const int* in_sizes, int n_in,
                              void* d_out, int out_size, void* d_ws, size_t ws_size,
                              hipStream_t stream) {
    const float* x     = (const float*)d_in[0];
    const float* pos   = (const float*)d_in[1];
    const int*   ei    = (const int*)d_in[2];
    const float* W     = (const float*)d_in[3];
    const float* b     = (const float*)d_in[4];
    const float* gamma = (const float*)d_in[5];
    const float* beta  = (const float*)d_in[6];
    float* out = (float*)d_out;

    const int n = in_sizes[0] / 64;   // 262144
    const int E = in_sizes[2] / 2;    // 4194304
    char* ws = (char*)d_ws;

    const size_t NEED_NEW = 70643712;
    if (ws_size >= NEED_NEW) {
        // New layout (bytes):
        //   h16      @ 0          : 33,554,432
        //   pairs    @ 33,554,432 : 33,554,432  (1024 x 8192 u32; reused as pooled16)
        //   partials @ 67,108,864 : 524,288
        //   stats2   @ 67,633,152 : 1,024
        //   cursor   @ 67,634,176 : 65,536      (1024 x 16-int line-padded)
        //   vcursor  @ 67,699,712 : 128,000     (8000 x 4-int padded)
        //   vlist    @ 67,827,712 : 2,816,000   -> end 70,643,712
        unsigned short* h16      = (unsigned short*)(ws + 0);
        unsigned int*   pairs    = (unsigned int*)(ws + 33554432);
        unsigned short* pooled16 = (unsigned short*)(ws + 33554432);
        float*          partials = (float*)(ws + 67108864);
        float*          stats2   = (float*)(ws + 67633152);
        int*            cursor   = (int*)(ws + 67634176);
        int*            vcursor  = (int*)(ws + 67699712);
        int*            vlist    = (int*)(ws + 67827712);

        k_zero<<<189, 256, 0, stream>>>(cursor, 48384);  // cursor + vcursor contiguous
        k0_gemm<<<GEMM_BLOCKS + XTRA_BLOCKS, 512, 0, stream>>>(
            x, W, b, h16, partials, n >> 4, pos, vcursor, vlist);
        k_bin2<<<E / BIN_EPB, 1024, 0, stream>>>(ei, ei + E, cursor, pairs);
        k_pool_new<<<NBUCK + 1, 1024, 0, stream>>>(pairs, cursor, h16, stats2, pooled16,
                                                   partials, gamma, beta, 1.0f / (float)n);
        k_vox<<<NVOX / 4, 256, 0, stream>>>(pooled16, vlist, vcursor, pos, stats2, out);
    } else {
        // Fallback: R2-verified layout/path
        unsigned short* h16      = (unsigned short*)(ws + 0);
        unsigned int*   pairs    = (unsigned int*)(ws + 33554432);
        float*          partials = (float*)(ws + 54525952);
        float*          stats2   = (float*)(ws + 55050240);
        int*            cursor   = (int*)(ws + 55051264);
        float*          xs       = (float*)(ws + 55055360);
        float*          ps       = (float*)(ws + 57103360);
        float*          cnt      = (float*)(ws + 57199360);
        float4*         zero4    = (float4*)(ws + 55055360);
        const int zero_n4 = (57231360 - 55055360) / 16;

        k_zero<<<4, 256, 0, stream>>>(cursor, NBUCK);
        k0_fused_old<<<2 * GEMM_BLOCKS + XTRA_BLOCKS, 256, 0, stream>>>(
            x, W, b, h16, partials, n >> 4, ei, ei + E, cursor, pairs, zero4, zero_n4);
        k3_finalize<<<1, 1024, 0, stream>>>(partials, gamma, beta, stats2, 1.0f / (float)n);
        k_pool_old<<<NBUCK, 1024, 0, stream>>>(pairs, cursor, h16, pos, stats2, xs, ps, cnt);
        k7_out<<<(out_size + 255) / 256, 256, 0, stream>>>(xs, ps, cnt, out, out_size);
    }
}

// Round 9
// 310.349 us; speedup vs baseline: 1.1170x; 1.0036x over previous
//
#include <hip/hip_runtime.h>
#include <hip/hip_fp16.h>

#define NVOX_DIM 20
#define NVOX 8000
#define BN_EPS 1e-5f

#define NBUCK 1024        // buckets = col >> 8
#define BSHIFT 8
#define NODES_PER_BUCK 256
#define GEMM_BLOCKS 1024
#define BIN_BLOCKS 512
#define XTRA_BLOCKS 64
#define CAP_NEW 8192      // slab slots/bucket (32 KB) -> reused as pooled u16 rows
#define CAP_OLD 5120
#define VCAP 88           // nodes/voxel capacity: mean 32.8, sigma 5.7, exp-max ~57
#define CSTRIDE 16        // cursor padding: one 64B line per bucket counter
#define VSTRIDE 4         // vcursor padding: 16B per voxel counter
#define BIN_EPB 8192      // edges per bin role block (fused kernel)

typedef _Float16 f16x8 __attribute__((ext_vector_type(8)));
typedef float f32x4 __attribute__((ext_vector_type(4)));

// order-preserving u16 key for half bits: neg -> ~b, pos -> b|0x8000
__device__ __forceinline__ unsigned short f2key(float v) {
    unsigned short hb = __half_as_ushort(__float2half(v));
    unsigned short m = (unsigned short)(0x8000u | (unsigned short)(-(int)(hb >> 15)));
    return (unsigned short)(hb ^ m);
}

__device__ __forceinline__ float key2f(unsigned int k) {
    unsigned short hb = (k & 0x8000u) ? (unsigned short)(k ^ 0x8000u)
                                      : (unsigned short)(0xFFFFu ^ k);
    __half_raw hr;
    hr.x = hb;
    return __half2float((__half)hr);
}

__device__ __forceinline__ f16x8 pack8(float4 a, float4 b) {
    f16x8 r;
    r[0] = (_Float16)a.x; r[1] = (_Float16)a.y; r[2] = (_Float16)a.z; r[3] = (_Float16)a.w;
    r[4] = (_Float16)b.x; r[5] = (_Float16)b.y; r[6] = (_Float16)b.z; r[7] = (_Float16)b.w;
    return r;
}

// one 16-row group (fallback path): 8 MFMAs + stats + scattered u16-key stores
__device__ __forceinline__ void gemm_step(int row0, f16x8 a0, f16x8 a1,
                                          const f16x8 (&bf)[4][2], const float (&bv)[4],
                                          float (&s)[4], float (&s2)[4],
                                          unsigned short* __restrict__ h16,
                                          int l15, int q) {
#pragma unroll
    for (int t4 = 0; t4 < 4; ++t4) {
        f32x4 acc = {bv[t4], bv[t4], bv[t4], bv[t4]};
        acc = __builtin_amdgcn_mfma_f32_16x16x32_f16(a0, bf[t4][0], acc, 0, 0, 0);
        acc = __builtin_amdgcn_mfma_f32_16x16x32_f16(a1, bf[t4][1], acc, 0, 0, 0);
        s[t4] += acc[0] + acc[1] + acc[2] + acc[3];
        s2[t4] = fmaf(acc[0], acc[0], s2[t4]);
        s2[t4] = fmaf(acc[1], acc[1], s2[t4]);
        s2[t4] = fmaf(acc[2], acc[2], s2[t4]);
        s2[t4] = fmaf(acc[3], acc[3], s2[t4]);
#pragma unroll
        for (int r = 0; r < 4; ++r) {
            h16[(size_t)(row0 + q * 4 + r) * 64 + t4 * 16 + l15] = f2key(acc[r]);
        }
    }
}

// ---------------- K-1: zero an int region (cursors) --------------------------
__global__ __launch_bounds__(256) void k_zero(int* __restrict__ p, int n) {
    int i = blockIdx.x * 256 + threadIdx.x;
    if (i < n) p[i] = 0;
}

// ---------------- K_front: fused [GEMM+stats | edge-bin | node->voxel bin] ---
// 512-thread blocks. Role by bid, interleaved 2:1 for co-residency:
//   bid < 1536: (bid%3)<2 -> GEMM (gb = (bid/3)*2 + bid%3), else BIN (bb=bid/3)
//   bid >= 1536: node->voxel binning (zb = bid-1536)
// GEMM (x-read BW-bound, MFMA) and BIN (LDS-atomic/scatter) are data-
// independent and pipe-complementary; co-residency overlaps them (~max vs sum).
// LDS is a union (45 KB) -> 3 blocks/CU.
// Pooling raw h before BN+ReLU downstream is valid: scale > 0 => BN+ReLU
// monotone nondecreasing per channel, commutes with max.
__global__ __launch_bounds__(512) void k_front(const float* __restrict__ x,
                                               const float* __restrict__ W,
                                               const float* __restrict__ bias,
                                               unsigned short* __restrict__ h16,
                                               float* __restrict__ partials, int n16,
                                               const int* __restrict__ rows,
                                               const int* __restrict__ cols,
                                               int* __restrict__ cursor,
                                               unsigned int* __restrict__ pairs,
                                               const float* __restrict__ pos,
                                               int* __restrict__ vcursor,
                                               int* __restrict__ vlist) {
    union SharedU {
        struct {
            float sW[4096];
            float red[2][8][64];
            unsigned short stg[8][16][65];
        } g;                                   // 37,120 B
        struct {
            unsigned int buf[BIN_EPB];         // 32,768 B
            int hist[NBUCK];
            int wpos[NBUCK];
            int gbase[NBUCK];
            int wsum[8];
        } b;                                   // 45,088 B
    };
    __shared__ SharedU su;
    int t = threadIdx.x;
    int bid = blockIdx.x;
    int lane = t & 63;
    int w = t >> 6;  // wave 0..7

    if (bid >= GEMM_BLOCKS + BIN_BLOCKS) {
        // -------- node -> voxel binning (reads only pos) --------
        int zb = bid - (GEMM_BLOCKS + BIN_BLOCKS);
        int nNodes = n16 * 16;
        for (int nd = zb * 512 + t; nd < nNodes; nd += XTRA_BLOCKS * 512) {
            float px = pos[(size_t)nd * 3 + 0];
            float py = pos[(size_t)nd * 3 + 1];
            float pz = pos[(size_t)nd * 3 + 2];
            int v0 = min(max((int)floorf(px * 2.f), 0), NVOX_DIM - 1);
            int v1 = min(max((int)floorf(py * 2.f), 0), NVOX_DIM - 1);
            int v2 = min(max((int)floorf(pz * 2.f), 0), NVOX_DIM - 1);
            int vox = (v0 * NVOX_DIM + v1) * NVOX_DIM + v2;
            int idx = atomicAdd(&vcursor[vox * VSTRIDE], 1);
            if (idx < VCAP) vlist[vox * VCAP + idx] = nd;
        }
        return;
    }

    if ((bid % 3) == 2) {
        // -------- edge-bin role: 8192 edges, in-LDS partition, run flush -----
        int bb = bid / 3;
        su.b.hist[t] = 0;
        su.b.hist[t + 512] = 0;
        __syncthreads();

        int base_e = bb * BIN_EPB + t * 16;
        int r[16], c[16];
#pragma unroll
        for (int g4 = 0; g4 < 4; ++g4) {
            int e = base_e + g4 * 4;
            int4 r4 = *(const int4*)(rows + e);
            int4 c4 = *(const int4*)(cols + e);
            r[g4 * 4 + 0] = r4.x; c[g4 * 4 + 0] = c4.x;
            r[g4 * 4 + 1] = r4.y; c[g4 * 4 + 1] = c4.y;
            r[g4 * 4 + 2] = r4.z; c[g4 * 4 + 2] = c4.z;
            r[g4 * 4 + 3] = r4.w; c[g4 * 4 + 3] = c4.w;
        }
#pragma unroll
        for (int i = 0; i < 16; ++i) atomicAdd(&su.b.hist[c[i] >> BSHIFT], 1);
        __syncthreads();

        // exclusive scan: thread t owns buckets 2t, 2t+1 (8 waves of 64)
        int c0 = su.b.hist[2 * t];
        int c1 = su.b.hist[2 * t + 1];
        int p = c0 + c1;
        int inc = p;
        for (int d = 1; d < 64; d <<= 1) {
            int u = __shfl_up(inc, d, 64);
            if (lane >= d) inc += u;
        }
        if (lane == 63) su.b.wsum[w] = inc;
        __syncthreads();
        int add = 0;
        for (int ww = 0; ww < w; ++ww) add += su.b.wsum[ww];
        int base = inc - p + add;
        su.b.wpos[2 * t] = base;
        su.b.wpos[2 * t + 1] = base + c0;
        su.b.gbase[2 * t] = atomicAdd(&cursor[(2 * t) * CSTRIDE], c0);
        su.b.gbase[2 * t + 1] = atomicAdd(&cursor[(2 * t + 1) * CSTRIDE], c1);
        __syncthreads();

        // scatter into LDS, bucket-major
#pragma unroll
        for (int i = 0; i < 16; ++i) {
            int bkt = c[i] >> BSHIFT;
            int idx = atomicAdd(&su.b.wpos[bkt], 1);
            su.b.buf[idx] = ((unsigned int)r[i] << 8) |
                            (unsigned int)(c[i] & (NODES_PER_BUCK - 1));
        }
        __syncthreads();

        // flush: each wave owns 128 buckets; contiguous run per bucket
        for (int it = 0; it < 128; ++it) {
            int j = w * 128 + it;
            int cnt = su.b.hist[j];
            int src = su.b.wpos[j] - cnt;   // wpos now == base + cnt
            int dst0 = su.b.gbase[j];
            for (int k2 = lane; k2 < cnt; k2 += 64) {
                int d = dst0 + k2;
                if (d < CAP_NEW) pairs[(size_t)j * CAP_NEW + d] = su.b.buf[src + k2];
            }
        }
        return;
    }

    // -------- GEMM role: h = x@W + b via MFMA -> u16 keys + stat partials ----
    int gb = (bid / 3) * 2 + (bid % 3);
    for (int i = t; i < 4096; i += 512) su.g.sW[i] = W[i];
    __syncthreads();
    int l15 = lane & 15;
    int q = lane >> 4;

    f16x8 bf[4][2];
#pragma unroll
    for (int t4 = 0; t4 < 4; ++t4)
#pragma unroll
        for (int kb = 0; kb < 2; ++kb)
#pragma unroll
            for (int i = 0; i < 8; ++i)
                bf[t4][kb][i] = (_Float16)su.g.sW[(kb * 32 + q * 8 + i) * 64 + t4 * 16 + l15];
    float bv[4];
#pragma unroll
    for (int t4 = 0; t4 < 4; ++t4) bv[t4] = bias[t4 * 16 + l15];

    float s[4] = {0.f, 0.f, 0.f, 0.f}, s2[4] = {0.f, 0.f, 0.f, 0.f};

    for (int g = gb * 8 + w; g < n16; g += GEMM_BLOCKS * 8) {
        int row0 = g * 16;
        const float* xp = x + (size_t)(row0 + l15) * 64 + q * 8;
        float4 xa = *(const float4*)(xp);
        float4 xb = *(const float4*)(xp + 4);
        float4 xc = *(const float4*)(xp + 32);
        float4 xd = *(const float4*)(xp + 36);
        f16x8 a0 = pack8(xa, xb), a1 = pack8(xc, xd);

#pragma unroll
        for (int t4 = 0; t4 < 4; ++t4) {
            f32x4 acc = {bv[t4], bv[t4], bv[t4], bv[t4]};
            acc = __builtin_amdgcn_mfma_f32_16x16x32_f16(a0, bf[t4][0], acc, 0, 0, 0);
            acc = __builtin_amdgcn_mfma_f32_16x16x32_f16(a1, bf[t4][1], acc, 0, 0, 0);
            s[t4] += acc[0] + acc[1] + acc[2] + acc[3];
            s2[t4] = fmaf(acc[0], acc[0], s2[t4]);
            s2[t4] = fmaf(acc[1], acc[1], s2[t4]);
            s2[t4] = fmaf(acc[2], acc[2], s2[t4]);
            s2[t4] = fmaf(acc[3], acc[3], s2[t4]);
#pragma unroll
            for (int r = 0; r < 4; ++r)
                su.g.stg[w][q * 4 + r][t4 * 16 + l15] = f2key(acc[r]);
        }
        // flush: 16 coalesced 128-B row stores (same-wave LDS transpose)
#pragma unroll
        for (int i = 0; i < 16; ++i)
            h16[(size_t)(row0 + i) * 64 + lane] = su.g.stg[w][i][lane];
    }

#pragma unroll
    for (int t4 = 0; t4 < 4; ++t4) {
        s[t4] += __shfl_xor(s[t4], 16, 64);
        s[t4] += __shfl_xor(s[t4], 32, 64);
        s2[t4] += __shfl_xor(s2[t4], 16, 64);
        s2[t4] += __shfl_xor(s2[t4], 32, 64);
    }
    if (lane < 16) {
#pragma unroll
        for (int t4 = 0; t4 < 4; ++t4) {
            su.g.red[0][w][t4 * 16 + lane] = s[t4];
            su.g.red[1][w][t4 * 16 + lane] = s2[t4];
        }
    }
    __syncthreads();
    if (t < 128) {
        int c = t & 63;
        int which = t >> 6;
        float v = 0.f;
#pragma unroll
        for (int ww = 0; ww < 8; ++ww) v += su.g.red[which][ww][c];
        partials[(size_t)gb * 128 + which * 64 + c] = v;
    }
}

// ---------------- K_pool: tile + LDS atomicMax, 32-deep gather batches -------
__global__ __launch_bounds__(1024) void k_pool_new(const unsigned int* __restrict__ pairs_,
                                                   const int* __restrict__ cursor,
                                                   const unsigned short* __restrict__ h16,
                                                   float* __restrict__ stats2,
                                                   unsigned short* __restrict__ pooled16,
                                                   const float* __restrict__ partials,
                                                   const float* __restrict__ gamma,
                                                   const float* __restrict__ beta,
                                                   float invN) {
    __shared__ unsigned int tile[NODES_PER_BUCK * 64];  // 64 KB
    int b = blockIdx.x;
    int t = threadIdx.x;

    if (b == NBUCK) {
        float* fred = (float*)tile;          // [8][128]
        float* tot = ((float*)tile) + 1024;  // [128]
        int c = t & 127;
        int g = t >> 7;
        float s = 0.f;
        for (int pb = g; pb < GEMM_BLOCKS; pb += 8) s += partials[(size_t)pb * 128 + c];
        fred[g * 128 + c] = s;
        __syncthreads();
        if (t < 128) {
            float v = 0.f;
#pragma unroll
            for (int g2 = 0; g2 < 8; ++g2) v += fred[g2 * 128 + t];
            tot[t] = v;
        }
        __syncthreads();
        if (t < 64) {
            float mean = tot[t] * invN;
            float var = tot[64 + t] * invN - mean * mean;
            float sc = gamma[t] * rsqrtf(var + BN_EPS);
            stats2[t] = sc;
            stats2[64 + t] = beta[t] - mean * sc;
        }
        return;
    }

    int lane = t & 63;
    int w = t >> 6;

    const unsigned int* src = (const unsigned int*)(h16 + (size_t)b * (NODES_PER_BUCK * 64));
#pragma unroll
    for (int k = 0; k < 8; ++k) {
        int i = t + k * 1024;
        unsigned int u = src[i];
        tile[2 * i] = u & 0xFFFFu;
        tile[2 * i + 1] = u >> 16;
    }
    __syncthreads();

    int cntE = min(cursor[b * CSTRIDE], CAP_NEW);
    int start = b * CAP_NEW;
    int end = start + cntE;
    int chunk = (cntE + 15) >> 4;
    int cs = start + w * chunk;
    int ce = min(cs + chunk, end);
    for (int j0 = cs; j0 < ce; j0 += 64) {
        int lim = min(64, ce - j0);
        unsigned int pk = (lane < lim) ? pairs_[j0 + lane] : 0u;
        int jj = 0;
        for (; jj + 32 <= lim; jj += 32) {
            unsigned int qv[32];
            unsigned int vv[32];
#pragma unroll
            for (int u = 0; u < 32; ++u)
                qv[u] = (unsigned int)__builtin_amdgcn_readlane((int)pk, jj + u);
#pragma unroll
            for (int u = 0; u < 32; ++u)
                vv[u] = (unsigned int)h16[(size_t)(qv[u] >> 8) * 64 + lane];
#pragma unroll
            for (int u = 0; u < 32; ++u)
                atomicMax(&tile[((qv[u] & 255u) << 6) + lane], vv[u]);
        }
        for (; jj + 8 <= lim; jj += 8) {
            unsigned int qv[8];
            unsigned int vv[8];
#pragma unroll
            for (int u = 0; u < 8; ++u)
                qv[u] = (unsigned int)__builtin_amdgcn_readlane((int)pk, jj + u);
#pragma unroll
            for (int u = 0; u < 8; ++u)
                vv[u] = (unsigned int)h16[(size_t)(qv[u] >> 8) * 64 + lane];
#pragma unroll
            for (int u = 0; u < 8; ++u)
                atomicMax(&tile[((qv[u] & 255u) << 6) + lane], vv[u]);
        }
        for (; jj < lim; ++jj) {
            unsigned int qq = (unsigned int)__builtin_amdgcn_readlane((int)pk, jj);
            unsigned int v = h16[(size_t)(qq >> 8) * 64 + lane];
            atomicMax(&tile[((qq & 255u) << 6) + lane], v);
        }
    }
    __syncthreads();  // all pairs reads done before slab overwrite

#pragma unroll
    for (int nl = 0; nl < NODES_PER_BUCK; nl += 16) {
        int node_l = nl + w;
        pooled16[((size_t)((b << BSHIFT) + node_l)) * 64 + lane] =
            (unsigned short)tile[(node_l << 6) + lane];
    }
}

// ---------------- K_vox: per-voxel gather-reduce, no atomics, fuses k7 -------
__global__ __launch_bounds__(256) void k_vox(const unsigned short* __restrict__ pooled16,
                                             const int* __restrict__ vlist,
                                             const int* __restrict__ vcursor,
                                             const float* __restrict__ pos,
                                             const float* __restrict__ stats2,
                                             float* __restrict__ out) {
    int v = blockIdx.x * 4 + (threadIdx.x >> 6);  // one wave per voxel
    int lane = threadIdx.x & 63;
    int cv = vcursor[v * VSTRIDE];
    int c = min(cv, VCAP);
    float scale = stats2[lane], shift = stats2[64 + lane];
    const int* lst = vlist + (size_t)v * VCAP;
    float s0 = 0.f, s1 = 0.f, s2 = 0.f, s3 = 0.f;
    int i = 0;
    for (; i + 4 <= c; i += 4) {
        int n0 = lst[i], n1 = lst[i + 1], n2 = lst[i + 2], n3 = lst[i + 3];
        float v0 = key2f(pooled16[(size_t)n0 * 64 + lane]);
        float v1 = key2f(pooled16[(size_t)n1 * 64 + lane]);
        float v2 = key2f(pooled16[(size_t)n2 * 64 + lane]);
        float v3 = key2f(pooled16[(size_t)n3 * 64 + lane]);
        s0 += fmaxf(fmaf(v0, scale, shift), 0.f);
        s1 += fmaxf(fmaf(v1, scale, shift), 0.f);
        s2 += fmaxf(fmaf(v2, scale, shift), 0.f);
        s3 += fmaxf(fmaf(v3, scale, shift), 0.f);
    }
    for (; i < c; ++i) {
        float v0 = key2f(pooled16[(size_t)lst[i] * 64 + lane]);
        s0 += fmaxf(fmaf(v0, scale, shift), 0.f);
    }
    float den = 1.f / fmaxf((float)cv, 1.f);
    out[(size_t)v * 67 + lane] = (s0 + s1 + s2 + s3) * den;
    if (lane < 3) {
        float p0 = 0.f, p1 = 0.f, p2 = 0.f, p3 = 0.f;
        int j = 0;
        for (; j + 4 <= c; j += 4) {
            p0 += pos[(size_t)lst[j] * 3 + lane];
            p1 += pos[(size_t)lst[j + 1] * 3 + lane];
            p2 += pos[(size_t)lst[j + 2] * 3 + lane];
            p3 += pos[(size_t)lst[j + 3] * 3 + lane];
        }
        for (; j < c; ++j) p0 += pos[(size_t)lst[j] * 3 + lane];
        out[(size_t)v * 67 + 64 + lane] = (p0 + p1 + p2 + p3) * den;
    }
}

// ================= fallback path (R2-verified) ===============================
__global__ __launch_bounds__(256) void k0_fused_old(const float* __restrict__ x,
                                                    const float* __restrict__ W,
                                                    const float* __restrict__ bias,
                                                    unsigned short* __restrict__ h16,
                                                    float* __restrict__ partials, int n16,
                                                    const int* __restrict__ rows,
                                                    const int* __restrict__ cols,
                                                    int* __restrict__ cursor,
                                                    unsigned int* __restrict__ pairs,
                                                    float4* __restrict__ zero_zone,
                                                    int zero_n4) {
    __shared__ float sW[4096];
    __shared__ float red[2][4][64];
    __shared__ int lh[NBUCK];
    __shared__ int lpos[NBUCK];
    int t = threadIdx.x;
    int bid = blockIdx.x;

    if (bid >= 2 * GEMM_BLOCKS) {
        int zb = bid - 2 * GEMM_BLOCKS;
        float4 z = {0.f, 0.f, 0.f, 0.f};
        for (int i = zb * 256 + t; i < zero_n4; i += XTRA_BLOCKS * 256) zero_zone[i] = z;
        return;
    }

    if (bid & 1) {
        int bb = bid >> 1;
        for (int j = t; j < NBUCK; j += 256) lh[j] = 0;
        __syncthreads();
        int base = bb * 4096 + t * 16;
        int r[16], c[16];
#pragma unroll
        for (int g4 = 0; g4 < 4; ++g4) {
            int e = base + g4 * 4;
            int4 r4 = *(const int4*)(rows + e);
            int4 c4 = *(const int4*)(cols + e);
            r[g4 * 4 + 0] = r4.x; c[g4 * 4 + 0] = c4.x;
            r[g4 * 4 + 1] = r4.y; c[g4 * 4 + 1] = c4.y;
            r[g4 * 4 + 2] = r4.z; c[g4 * 4 + 2] = c4.z;
            r[g4 * 4 + 3] = r4.w; c[g4 * 4 + 3] = c4.w;
        }
#pragma unroll
        for (int i = 0; i < 16; ++i) atomicAdd(&lh[c[i] >> BSHIFT], 1);
        __syncthreads();
        for (int j = t; j < NBUCK; j += 256) lpos[j] = atomicAdd(&cursor[j], lh[j]);
        __syncthreads();
#pragma unroll
        for (int i = 0; i < 16; ++i) {
            int bkt = c[i] >> BSHIFT;
            int idx = atomicAdd(&lpos[bkt], 1);
            if (idx < CAP_OLD)
                pairs[(size_t)bkt * CAP_OLD + idx] =
                    ((unsigned int)r[i] << 8) | (unsigned int)(c[i] & (NODES_PER_BUCK - 1));
        }
        return;
    }

    int gb = bid >> 1;
    for (int i = t; i < 4096; i += 256) sW[i] = W[i];
    __syncthreads();
    int lane = t & 63;
    int w = t >> 6;
    int l15 = lane & 15;
    int q = lane >> 4;

    f16x8 bf[4][2];
#pragma unroll
    for (int t4 = 0; t4 < 4; ++t4)
#pragma unroll
        for (int kb = 0; kb < 2; ++kb)
#pragma unroll
            for (int i = 0; i < 8; ++i)
                bf[t4][kb][i] = (_Float16)sW[(kb * 32 + q * 8 + i) * 64 + t4 * 16 + l15];
    float bv[4];
#pragma unroll
    for (int t4 = 0; t4 < 4; ++t4) bv[t4] = bias[t4 * 16 + l15];

    float s[4] = {0.f, 0.f, 0.f, 0.f}, s2[4] = {0.f, 0.f, 0.f, 0.f};

    for (int g = gb * 4 + w; g < n16; g += GEMM_BLOCKS * 4) {
        int row0 = g * 16;
        const float* xp = x + (size_t)(row0 + l15) * 64 + q * 8;
        float4 xa = *(const float4*)(xp);
        float4 xb = *(const float4*)(xp + 4);
        float4 xc = *(const float4*)(xp + 32);
        float4 xd = *(const float4*)(xp + 36);
        gemm_step(row0, pack8(xa, xb), pack8(xc, xd), bf, bv, s, s2, h16, l15, q);
    }

#pragma unroll
    for (int t4 = 0; t4 < 4; ++t4) {
        s[t4] += __shfl_xor(s[t4], 16, 64);
        s[t4] += __shfl_xor(s[t4], 32, 64);
        s2[t4] += __shfl_xor(s2[t4], 16, 64);
        s2[t4] += __shfl_xor(s2[t4], 32, 64);
    }
    if (lane < 16) {
#pragma unroll
        for (int t4 = 0; t4 < 4; ++t4) {
            red[0][w][t4 * 16 + lane] = s[t4];
            red[1][w][t4 * 16 + lane] = s2[t4];
        }
    }
    __syncthreads();
    if (t < 128) {
        int c = t & 63;
        int which = t >> 6;
        float v = red[which][0][c] + red[which][1][c] + red[which][2][c] + red[which][3][c];
        partials[(size_t)gb * 128 + which * 64 + c] = v;
    }
}

__global__ __launch_bounds__(1024) void k3_finalize(const float* __restrict__ partials,
                                                    const float* __restrict__ gamma,
                                                    const float* __restrict__ beta,
                                                    float* __restrict__ stats2, float invN) {
    __shared__ float red[8][128];
    __shared__ float tot[128];
    int t = threadIdx.x;
    int c = t & 127;
    int g = t >> 7;
    float s = 0.f;
    for (int b = g; b < GEMM_BLOCKS; b += 8) s += partials[(size_t)b * 128 + c];
    red[g][c] = s;
    __syncthreads();
    if (t < 128) {
        float v = 0.f;
#pragma unroll
        for (int g2 = 0; g2 < 8; ++g2) v += red[g2][t];
        tot[t] = v;
    }
    __syncthreads();
    if (t < 64) {
        float mean = tot[t] * invN;
        float var = tot[64 + t] * invN - mean * mean;
        float sc = gamma[t] * rsqrtf(var + BN_EPS);
        stats2[t] = sc;
        stats2[64 + t] = beta[t] - mean * sc;
    }
}

__global__ __launch_bounds__(1024) void k_pool_old(const unsigned int* __restrict__ pairs_,
                                                   const int* __restrict__ cursor,
                                                   const unsigned short* __restrict__ h16,
                                                   const float* __restrict__ pos,
                                                   const float* __restrict__ stats2,
                                                   float* __restrict__ xs,
                                                   float* __restrict__ ps,
                                                   float* __restrict__ cnt) {
    __shared__ unsigned int tile[NODES_PER_BUCK * 64];
    int b = blockIdx.x;
    int t = threadIdx.x;
    int lane = t & 63;
    int w = t >> 6;
    float scale = stats2[lane];
    float shift = stats2[64 + lane];

    const unsigned int* src = (const unsigned int*)(h16 + (size_t)b * (NODES_PER_BUCK * 64));
#pragma unroll
    for (int k = 0; k < 8; ++k) {
        int i = t + k * 1024;
        unsigned int u = src[i];
        tile[2 * i] = u & 0xFFFFu;
        tile[2 * i + 1] = u >> 16;
    }
    __syncthreads();

    int cntE = min(cursor[b], CAP_OLD);
    int start = b * CAP_OLD;
    int end = start + cntE;
    int chunk = (cntE + 15) >> 4;
    int cs = start + w * chunk;
    int ce = min(cs + chunk, end);
    for (int j0 = cs; j0 < ce; j0 += 64) {
        int lim = min(64, ce - j0);
        unsigned int pk = (lane < lim) ? pairs_[j0 + lane] : 0u;
        int jj = 0;
        for (; jj + 16 <= lim; jj += 16) {
            unsigned int qv[16];
            unsigned short vv[16];
#pragma unroll
            for (int u = 0; u < 16; ++u)
                qv[u] = (unsigned int)__builtin_amdgcn_readlane((int)pk, jj + u);
#pragma unroll
            for (int u = 0; u < 16; ++u) vv[u] = h16[(size_t)(qv[u] >> 8) * 64 + lane];
#pragma unroll
            for (int u = 0; u < 16; ++u)
                atomicMax(&tile[((qv[u] & 255u) << 6) + lane], (unsigned int)vv[u]);
        }
        for (; jj < lim; ++jj) {
            unsigned int qq = (unsigned int)__builtin_amdgcn_readlane((int)pk, jj);
            unsigned int v = h16[(size_t)(qq >> 8) * 64 + lane];
            atomicMax(&tile[((qq & 255u) << 6) + lane], v);
        }
    }
    __syncthreads();

#pragma unroll
    for (int nl = 0; nl < NODES_PER_BUCK; nl += 16) {
        int node_l = nl + w;
        int c = (b << BSHIFT) + node_l;
        float px = pos[(size_t)c * 3 + 0];
        float py = pos[(size_t)c * 3 + 1];
        float pz = pos[(size_t)c * 3 + 2];
        int v0 = min(max((int)floorf(px * 2.f), 0), NVOX_DIM - 1);
        int v1 = min(max((int)floorf(py * 2.f), 0), NVOX_DIM - 1);
        int v2 = min(max((int)floorf(pz * 2.f), 0), NVOX_DIM - 1);
        int vox = (v0 * NVOX_DIM + v1) * NVOX_DIM + v2;
        float v = key2f(tile[(node_l << 6) + lane]);
        float val = fmaxf(fmaf(v, scale, shift), 0.f);
        atomicAdd(&xs[(size_t)vox * 64 + lane], val);
        if (lane < 3) atomicAdd(&ps[vox * 3 + lane], lane == 0 ? px : (lane == 1 ? py : pz));
        if (lane == 0) atomicAdd(&cnt[vox], 1.f);
    }
}

__global__ __launch_bounds__(256) void k7_out(const float* __restrict__ xs,
                                              const float* __restrict__ ps,
                                              const float* __restrict__ cnt,
                                              float* __restrict__ out, int total) {
    int idx = blockIdx.x * blockDim.x + threadIdx.x;
    if (idx >= total) return;
    int v = idx / 67;
    int c = idx - v * 67;
    float d = fmaxf(cnt[v], 1.f);
    float val = (c < 64) ? xs[(size_t)v * 64 + c] : ps[v * 3 + (c - 64)];
    out[idx] = val / d;
}

extern "C" void kernel_launch(void* const* d_in, const int* in_sizes, int n_in,
                              void* d_out, int out_size, void* d_ws, size_t ws_size,
                              hipStream_t stream) {
    const float* x     = (const float*)d_in[0];
    const float* pos   = (const float*)d_in[1];
    const int*   ei    = (const int*)d_in[2];
    const float* W     = (const float*)d_in[3];
    const float* b     = (const float*)d_in[4];
    const float* gamma = (const float*)d_in[5];
    const float* beta  = (const float*)d_in[6];
    float* out = (float*)d_out;

    const int n = in_sizes[0] / 64;   // 262144
    const int E = in_sizes[2] / 2;    // 4194304
    char* ws = (char*)d_ws;

    const size_t NEED_NEW = 70643712;
    if (ws_size >= NEED_NEW) {
        // Layout (bytes):
        //   h16      @ 0          : 33,554,432
        //   pairs    @ 33,554,432 : 33,554,432  (1024 x 8192 u32; reused as pooled16)
        //   partials @ 67,108,864 : 524,288
        //   stats2   @ 67,633,152 : 1,024
        //   cursor   @ 67,634,176 : 65,536      (1024 x 16-int line-padded)
        //   vcursor  @ 67,699,712 : 128,000     (8000 x 4-int padded)
        //   vlist    @ 67,827,712 : 2,816,000   -> end 70,643,712
        unsigned short* h16      = (unsigned short*)(ws + 0);
        unsigned int*   pairs    = (unsigned int*)(ws + 33554432);
        unsigned short* pooled16 = (unsigned short*)(ws + 33554432);
        float*          partials = (float*)(ws + 67108864);
        float*          stats2   = (float*)(ws + 67633152);
        int*            cursor   = (int*)(ws + 67634176);
        int*            vcursor  = (int*)(ws + 67699712);
        int*            vlist    = (int*)(ws + 67827712);

        k_zero<<<189, 256, 0, stream>>>(cursor, 48384);  // cursor + vcursor contiguous
        k_front<<<GEMM_BLOCKS + BIN_BLOCKS + XTRA_BLOCKS, 512, 0, stream>>>(
            x, W, b, h16, partials, n >> 4, ei, ei + E, cursor, pairs,
            pos, vcursor, vlist);
        k_pool_new<<<NBUCK + 1, 1024, 0, stream>>>(pairs, cursor, h16, stats2, pooled16,
                                                   partials, gamma, beta, 1.0f / (float)n);
        k_vox<<<NVOX / 4, 256, 0, stream>>>(pooled16, vlist, vcursor, pos, stats2, out);
    } else {
        // Fallback: R2-verified layout/path
        unsigned short* h16      = (unsigned short*)(ws + 0);
        unsigned int*   pairs    = (unsigned int*)(ws + 33554432);
        float*          partials = (float*)(ws + 54525952);
        float*          stats2   = (float*)(ws + 55050240);
        int*            cursor   = (int*)(ws + 55051264);
        float*          xs       = (float*)(ws + 55055360);
        float*          ps       = (float*)(ws + 57103360);
        float*          cnt      = (float*)(ws + 57199360);
        float4*         zero4    = (float4*)(ws + 55055360);
        const int zero_n4 = (57231360 - 55055360) / 16;

        k_zero<<<4, 256, 0, stream>>>(cursor, NBUCK);
        k0_fused_old<<<2 * GEMM_BLOCKS + XTRA_BLOCKS, 256, 0, stream>>>(
            x, W, b, h16, partials, n >> 4, ei, ei + E, cursor, pairs, zero4, zero_n4);
        k3_finalize<<<1, 1024, 0, stream>>>(partials, gamma, beta, stats2, 1.0f / (float)n);
        k_pool_old<<<NBUCK, 1024, 0, stream>>>(pairs, cursor, h16, pos, stats2, xs, ps, cnt);
        k7_out<<<(out_size + 255) / 256, 256, 0, stream>>>(xs, ps, cnt, out, out_size);
    }
}

// Round 10
// 307.568 us; speedup vs baseline: 1.1271x; 1.0090x over previous
//
#include <hip/hip_runtime.h>
#include <hip/hip_fp16.h>

#define NVOX_DIM 20
#define NVOX 8000
#define BN_EPS 1e-5f

#define NBUCK 1024        // buckets = col >> 8
#define BSHIFT 8
#define NODES_PER_BUCK 256
#define GEMM_BLOCKS 1024
#define BIN_BLOCKS 512
#define XTRA_BLOCKS 64
#define CAP_NEW 8192      // slab slots/bucket (32 KB) -> reused as pooled u16 rows
#define CAP_OLD 5120
#define VCAP 88           // nodes/voxel capacity: mean 32.8, sigma 5.7, exp-max ~57
#define CSTRIDE 16        // cursor padding: one 64B line per bucket counter
#define VSTRIDE 4         // vcursor padding: 16B per voxel counter
#define BIN_EPB 8192      // edges per bin role block (fused kernel)

typedef _Float16 f16x8 __attribute__((ext_vector_type(8)));
typedef float f32x4 __attribute__((ext_vector_type(4)));

// order-preserving u16 key for half bits: neg -> ~b, pos -> b|0x8000
__device__ __forceinline__ unsigned short f2key(float v) {
    unsigned short hb = __half_as_ushort(__float2half(v));
    unsigned short m = (unsigned short)(0x8000u | (unsigned short)(-(int)(hb >> 15)));
    return (unsigned short)(hb ^ m);
}

__device__ __forceinline__ float key2f(unsigned int k) {
    unsigned short hb = (k & 0x8000u) ? (unsigned short)(k ^ 0x8000u)
                                      : (unsigned short)(0xFFFFu ^ k);
    __half_raw hr;
    hr.x = hb;
    return __half2float((__half)hr);
}

__device__ __forceinline__ f16x8 pack8(float4 a, float4 b) {
    f16x8 r;
    r[0] = (_Float16)a.x; r[1] = (_Float16)a.y; r[2] = (_Float16)a.z; r[3] = (_Float16)a.w;
    r[4] = (_Float16)b.x; r[5] = (_Float16)b.y; r[6] = (_Float16)b.z; r[7] = (_Float16)b.w;
    return r;
}

// one 16-row group (fallback path): 8 MFMAs + stats + scattered u16-key stores
__device__ __forceinline__ void gemm_step(int row0, f16x8 a0, f16x8 a1,
                                          const f16x8 (&bf)[4][2], const float (&bv)[4],
                                          float (&s)[4], float (&s2)[4],
                                          unsigned short* __restrict__ h16,
                                          int l15, int q) {
#pragma unroll
    for (int t4 = 0; t4 < 4; ++t4) {
        f32x4 acc = {bv[t4], bv[t4], bv[t4], bv[t4]};
        acc = __builtin_amdgcn_mfma_f32_16x16x32_f16(a0, bf[t4][0], acc, 0, 0, 0);
        acc = __builtin_amdgcn_mfma_f32_16x16x32_f16(a1, bf[t4][1], acc, 0, 0, 0);
        s[t4] += acc[0] + acc[1] + acc[2] + acc[3];
        s2[t4] = fmaf(acc[0], acc[0], s2[t4]);
        s2[t4] = fmaf(acc[1], acc[1], s2[t4]);
        s2[t4] = fmaf(acc[2], acc[2], s2[t4]);
        s2[t4] = fmaf(acc[3], acc[3], s2[t4]);
#pragma unroll
        for (int r = 0; r < 4; ++r) {
            h16[(size_t)(row0 + q * 4 + r) * 64 + t4 * 16 + l15] = f2key(acc[r]);
        }
    }
}

// ---------------- K-1: zero an int region (cursors) --------------------------
__global__ __launch_bounds__(256) void k_zero(int* __restrict__ p, int n) {
    int i = blockIdx.x * 256 + threadIdx.x;
    if (i < n) p[i] = 0;
}

// ---------------- K_front: fused [GEMM+stats | edge-bin | node->voxel bin] ---
// 512-thread blocks. Role by bid, interleaved 2:1 for co-residency:
//   bid < 1536: (bid%3)<2 -> GEMM (gb = (bid/3)*2 + bid%3), else BIN (bb=bid/3)
//   bid >= 1536: node->voxel binning (zb = bid-1536)
// GEMM role is software-pipelined for the common n16==16384 case: both outer
// iterations' 8 float4 loads issue before any compute (branch-free, no VGPR
// cap — avoids R7's two failure causes).
// Pooling raw h before BN+ReLU downstream is valid: scale > 0 => BN+ReLU
// monotone nondecreasing per channel, commutes with max.
__global__ __launch_bounds__(512) void k_front(const float* __restrict__ x,
                                               const float* __restrict__ W,
                                               const float* __restrict__ bias,
                                               unsigned short* __restrict__ h16,
                                               float* __restrict__ partials, int n16,
                                               const int* __restrict__ rows,
                                               const int* __restrict__ cols,
                                               int* __restrict__ cursor,
                                               unsigned int* __restrict__ pairs,
                                               const float* __restrict__ pos,
                                               int* __restrict__ vcursor,
                                               int* __restrict__ vlist) {
    union SharedU {
        struct {
            float sW[4096];
            float red[2][8][64];
            unsigned short stg[8][16][65];
        } g;                                   // 37,120 B
        struct {
            unsigned int buf[BIN_EPB];         // 32,768 B
            int hist[NBUCK];
            int wpos[NBUCK];
            int gbase[NBUCK];
            int wsum[8];
        } b;                                   // 45,088 B
    };
    __shared__ SharedU su;
    int t = threadIdx.x;
    int bid = blockIdx.x;
    int lane = t & 63;
    int w = t >> 6;  // wave 0..7

    if (bid >= GEMM_BLOCKS + BIN_BLOCKS) {
        // -------- node -> voxel binning (reads only pos) --------
        int zb = bid - (GEMM_BLOCKS + BIN_BLOCKS);
        int nNodes = n16 * 16;
        for (int nd = zb * 512 + t; nd < nNodes; nd += XTRA_BLOCKS * 512) {
            float px = pos[(size_t)nd * 3 + 0];
            float py = pos[(size_t)nd * 3 + 1];
            float pz = pos[(size_t)nd * 3 + 2];
            int v0 = min(max((int)floorf(px * 2.f), 0), NVOX_DIM - 1);
            int v1 = min(max((int)floorf(py * 2.f), 0), NVOX_DIM - 1);
            int v2 = min(max((int)floorf(pz * 2.f), 0), NVOX_DIM - 1);
            int vox = (v0 * NVOX_DIM + v1) * NVOX_DIM + v2;
            int idx = atomicAdd(&vcursor[vox * VSTRIDE], 1);
            if (idx < VCAP) vlist[vox * VCAP + idx] = nd;
        }
        return;
    }

    if ((bid % 3) == 2) {
        // -------- edge-bin role: 8192 edges, in-LDS partition, run flush -----
        int bb = bid / 3;
        su.b.hist[t] = 0;
        su.b.hist[t + 512] = 0;
        __syncthreads();

        int base_e = bb * BIN_EPB + t * 16;
        int r[16], c[16];
#pragma unroll
        for (int g4 = 0; g4 < 4; ++g4) {
            int e = base_e + g4 * 4;
            int4 r4 = *(const int4*)(rows + e);
            int4 c4 = *(const int4*)(cols + e);
            r[g4 * 4 + 0] = r4.x; c[g4 * 4 + 0] = c4.x;
            r[g4 * 4 + 1] = r4.y; c[g4 * 4 + 1] = c4.y;
            r[g4 * 4 + 2] = r4.z; c[g4 * 4 + 2] = c4.z;
            r[g4 * 4 + 3] = r4.w; c[g4 * 4 + 3] = c4.w;
        }
#pragma unroll
        for (int i = 0; i < 16; ++i) atomicAdd(&su.b.hist[c[i] >> BSHIFT], 1);
        __syncthreads();

        // exclusive scan: thread t owns buckets 2t, 2t+1 (8 waves of 64)
        int c0 = su.b.hist[2 * t];
        int c1 = su.b.hist[2 * t + 1];
        int p = c0 + c1;
        int inc = p;
        for (int d = 1; d < 64; d <<= 1) {
            int u = __shfl_up(inc, d, 64);
            if (lane >= d) inc += u;
        }
        if (lane == 63) su.b.wsum[w] = inc;
        __syncthreads();
        int add = 0;
        for (int ww = 0; ww < w; ++ww) add += su.b.wsum[ww];
        int base = inc - p + add;
        su.b.wpos[2 * t] = base;
        su.b.wpos[2 * t + 1] = base + c0;
        su.b.gbase[2 * t] = atomicAdd(&cursor[(2 * t) * CSTRIDE], c0);
        su.b.gbase[2 * t + 1] = atomicAdd(&cursor[(2 * t + 1) * CSTRIDE], c1);
        __syncthreads();

        // scatter into LDS, bucket-major
#pragma unroll
        for (int i = 0; i < 16; ++i) {
            int bkt = c[i] >> BSHIFT;
            int idx = atomicAdd(&su.b.wpos[bkt], 1);
            su.b.buf[idx] = ((unsigned int)r[i] << 8) |
                            (unsigned int)(c[i] & (NODES_PER_BUCK - 1));
        }
        __syncthreads();

        // flush: each wave owns 128 buckets; contiguous run per bucket
        for (int it = 0; it < 128; ++it) {
            int j = w * 128 + it;
            int cnt = su.b.hist[j];
            int src = su.b.wpos[j] - cnt;   // wpos now == base + cnt
            int dst0 = su.b.gbase[j];
            for (int k2 = lane; k2 < cnt; k2 += 64) {
                int d = dst0 + k2;
                if (d < CAP_NEW) pairs[(size_t)j * CAP_NEW + d] = su.b.buf[src + k2];
            }
        }
        return;
    }

    // -------- GEMM role: h = x@W + b via MFMA -> u16 keys + stat partials ----
    int gb = (bid / 3) * 2 + (bid % 3);
    for (int i = t; i < 4096; i += 512) su.g.sW[i] = W[i];
    __syncthreads();
    int l15 = lane & 15;
    int q = lane >> 4;

    f16x8 bf[4][2];
#pragma unroll
    for (int t4 = 0; t4 < 4; ++t4)
#pragma unroll
        for (int kb = 0; kb < 2; ++kb)
#pragma unroll
            for (int i = 0; i < 8; ++i)
                bf[t4][kb][i] = (_Float16)su.g.sW[(kb * 32 + q * 8 + i) * 64 + t4 * 16 + l15];
    float bv[4];
#pragma unroll
    for (int t4 = 0; t4 < 4; ++t4) bv[t4] = bias[t4 * 16 + l15];

    float s[4] = {0.f, 0.f, 0.f, 0.f}, s2[4] = {0.f, 0.f, 0.f, 0.f};

    if (n16 == GEMM_BLOCKS * 16) {
        // exactly 2 iterations per wave, branch-free: pipeline both loads
        int g0 = gb * 8 + w;                  // < 8192
        int g1 = g0 + GEMM_BLOCKS * 8;        // < 16384
        const float* xp0 = x + (size_t)(g0 * 16 + l15) * 64 + q * 8;
        const float* xp1 = x + (size_t)(g1 * 16 + l15) * 64 + q * 8;
        float4 A0 = *(const float4*)(xp0);
        float4 A1 = *(const float4*)(xp0 + 4);
        float4 A2 = *(const float4*)(xp0 + 32);
        float4 A3 = *(const float4*)(xp0 + 36);
        float4 B0 = *(const float4*)(xp1);
        float4 B1 = *(const float4*)(xp1 + 4);
        float4 B2 = *(const float4*)(xp1 + 32);
        float4 B3 = *(const float4*)(xp1 + 36);

#pragma unroll
        for (int kk = 0; kk < 2; ++kk) {
            int row0 = (kk == 0 ? g0 : g1) * 16;
            f16x8 a0 = kk == 0 ? pack8(A0, A1) : pack8(B0, B1);
            f16x8 a1 = kk == 0 ? pack8(A2, A3) : pack8(B2, B3);
#pragma unroll
            for (int t4 = 0; t4 < 4; ++t4) {
                f32x4 acc = {bv[t4], bv[t4], bv[t4], bv[t4]};
                acc = __builtin_amdgcn_mfma_f32_16x16x32_f16(a0, bf[t4][0], acc, 0, 0, 0);
                acc = __builtin_amdgcn_mfma_f32_16x16x32_f16(a1, bf[t4][1], acc, 0, 0, 0);
                s[t4] += acc[0] + acc[1] + acc[2] + acc[3];
                s2[t4] = fmaf(acc[0], acc[0], s2[t4]);
                s2[t4] = fmaf(acc[1], acc[1], s2[t4]);
                s2[t4] = fmaf(acc[2], acc[2], s2[t4]);
                s2[t4] = fmaf(acc[3], acc[3], s2[t4]);
#pragma unroll
                for (int r = 0; r < 4; ++r)
                    su.g.stg[w][q * 4 + r][t4 * 16 + l15] = f2key(acc[r]);
            }
#pragma unroll
            for (int i = 0; i < 16; ++i)
                h16[(size_t)(row0 + i) * 64 + lane] = su.g.stg[w][i][lane];
        }
    } else {
        for (int g = gb * 8 + w; g < n16; g += GEMM_BLOCKS * 8) {
            int row0 = g * 16;
            const float* xp = x + (size_t)(row0 + l15) * 64 + q * 8;
            float4 xa = *(const float4*)(xp);
            float4 xb = *(const float4*)(xp + 4);
            float4 xc = *(const float4*)(xp + 32);
            float4 xd = *(const float4*)(xp + 36);
            f16x8 a0 = pack8(xa, xb), a1 = pack8(xc, xd);
#pragma unroll
            for (int t4 = 0; t4 < 4; ++t4) {
                f32x4 acc = {bv[t4], bv[t4], bv[t4], bv[t4]};
                acc = __builtin_amdgcn_mfma_f32_16x16x32_f16(a0, bf[t4][0], acc, 0, 0, 0);
                acc = __builtin_amdgcn_mfma_f32_16x16x32_f16(a1, bf[t4][1], acc, 0, 0, 0);
                s[t4] += acc[0] + acc[1] + acc[2] + acc[3];
                s2[t4] = fmaf(acc[0], acc[0], s2[t4]);
                s2[t4] = fmaf(acc[1], acc[1], s2[t4]);
                s2[t4] = fmaf(acc[2], acc[2], s2[t4]);
                s2[t4] = fmaf(acc[3], acc[3], s2[t4]);
#pragma unroll
                for (int r = 0; r < 4; ++r)
                    su.g.stg[w][q * 4 + r][t4 * 16 + l15] = f2key(acc[r]);
            }
#pragma unroll
            for (int i = 0; i < 16; ++i)
                h16[(size_t)(row0 + i) * 64 + lane] = su.g.stg[w][i][lane];
        }
    }

#pragma unroll
    for (int t4 = 0; t4 < 4; ++t4) {
        s[t4] += __shfl_xor(s[t4], 16, 64);
        s[t4] += __shfl_xor(s[t4], 32, 64);
        s2[t4] += __shfl_xor(s2[t4], 16, 64);
        s2[t4] += __shfl_xor(s2[t4], 32, 64);
    }
    if (lane < 16) {
#pragma unroll
        for (int t4 = 0; t4 < 4; ++t4) {
            su.g.red[0][w][t4 * 16 + lane] = s[t4];
            su.g.red[1][w][t4 * 16 + lane] = s2[t4];
        }
    }
    __syncthreads();
    if (t < 128) {
        int c = t & 63;
        int which = t >> 6;
        float v = 0.f;
#pragma unroll
        for (int ww = 0; ww < 8; ++ww) v += su.g.red[which][ww][c];
        partials[(size_t)gb * 128 + which * 64 + c] = v;
    }
}

// ---------------- K_pool: tile + LDS atomicMax, 32-deep gather batches -------
__global__ __launch_bounds__(1024) void k_pool_new(const unsigned int* __restrict__ pairs_,
                                                   const int* __restrict__ cursor,
                                                   const unsigned short* __restrict__ h16,
                                                   float* __restrict__ stats2,
                                                   unsigned short* __restrict__ pooled16,
                                                   const float* __restrict__ partials,
                                                   const float* __restrict__ gamma,
                                                   const float* __restrict__ beta,
                                                   float invN) {
    __shared__ unsigned int tile[NODES_PER_BUCK * 64];  // 64 KB
    int b = blockIdx.x;
    int t = threadIdx.x;

    if (b == NBUCK) {
        float* fred = (float*)tile;          // [8][128]
        float* tot = ((float*)tile) + 1024;  // [128]
        int c = t & 127;
        int g = t >> 7;
        float s = 0.f;
        for (int pb = g; pb < GEMM_BLOCKS; pb += 8) s += partials[(size_t)pb * 128 + c];
        fred[g * 128 + c] = s;
        __syncthreads();
        if (t < 128) {
            float v = 0.f;
#pragma unroll
            for (int g2 = 0; g2 < 8; ++g2) v += fred[g2 * 128 + t];
            tot[t] = v;
        }
        __syncthreads();
        if (t < 64) {
            float mean = tot[t] * invN;
            float var = tot[64 + t] * invN - mean * mean;
            float sc = gamma[t] * rsqrtf(var + BN_EPS);
            stats2[t] = sc;
            stats2[64 + t] = beta[t] - mean * sc;
        }
        return;
    }

    int lane = t & 63;
    int w = t >> 6;

    const unsigned int* src = (const unsigned int*)(h16 + (size_t)b * (NODES_PER_BUCK * 64));
#pragma unroll
    for (int k = 0; k < 8; ++k) {
        int i = t + k * 1024;
        unsigned int u = src[i];
        tile[2 * i] = u & 0xFFFFu;
        tile[2 * i + 1] = u >> 16;
    }
    __syncthreads();

    int cntE = min(cursor[b * CSTRIDE], CAP_NEW);
    int start = b * CAP_NEW;
    int end = start + cntE;
    int chunk = (cntE + 15) >> 4;
    int cs = start + w * chunk;
    int ce = min(cs + chunk, end);
    for (int j0 = cs; j0 < ce; j0 += 64) {
        int lim = min(64, ce - j0);
        unsigned int pk = (lane < lim) ? pairs_[j0 + lane] : 0u;
        int jj = 0;
        for (; jj + 32 <= lim; jj += 32) {
            unsigned int qv[32];
            unsigned int vv[32];
#pragma unroll
            for (int u = 0; u < 32; ++u)
                qv[u] = (unsigned int)__builtin_amdgcn_readlane((int)pk, jj + u);
#pragma unroll
            for (int u = 0; u < 32; ++u)
                vv[u] = (unsigned int)h16[(size_t)(qv[u] >> 8) * 64 + lane];
#pragma unroll
            for (int u = 0; u < 32; ++u)
                atomicMax(&tile[((qv[u] & 255u) << 6) + lane], vv[u]);
        }
        for (; jj + 8 <= lim; jj += 8) {
            unsigned int qv[8];
            unsigned int vv[8];
#pragma unroll
            for (int u = 0; u < 8; ++u)
                qv[u] = (unsigned int)__builtin_amdgcn_readlane((int)pk, jj + u);
#pragma unroll
            for (int u = 0; u < 8; ++u)
                vv[u] = (unsigned int)h16[(size_t)(qv[u] >> 8) * 64 + lane];
#pragma unroll
            for (int u = 0; u < 8; ++u)
                atomicMax(&tile[((qv[u] & 255u) << 6) + lane], vv[u]);
        }
        for (; jj < lim; ++jj) {
            unsigned int qq = (unsigned int)__builtin_amdgcn_readlane((int)pk, jj);
            unsigned int v = h16[(size_t)(qq >> 8) * 64 + lane];
            atomicMax(&tile[((qq & 255u) << 6) + lane], v);
        }
    }
    __syncthreads();  // all pairs reads done before slab overwrite

#pragma unroll
    for (int nl = 0; nl < NODES_PER_BUCK; nl += 16) {
        int node_l = nl + w;
        pooled16[((size_t)((b << BSHIFT) + node_l)) * 64 + lane] =
            (unsigned short)tile[(node_l << 6) + lane];
    }
}

// ---------------- K_vox: per-voxel gather-reduce, 8-deep, fuses k7 -----------
__global__ __launch_bounds__(256) void k_vox(const unsigned short* __restrict__ pooled16,
                                             const int* __restrict__ vlist,
                                             const int* __restrict__ vcursor,
                                             const float* __restrict__ pos,
                                             const float* __restrict__ stats2,
                                             float* __restrict__ out) {
    int v = blockIdx.x * 4 + (threadIdx.x >> 6);  // one wave per voxel
    int lane = threadIdx.x & 63;
    int cv = vcursor[v * VSTRIDE];
    int c = min(cv, VCAP);
    float scale = stats2[lane], shift = stats2[64 + lane];
    const int* lst = vlist + (size_t)v * VCAP;  // rows are 352 B = 16-B aligned
    float s0 = 0.f, s1 = 0.f, s2 = 0.f, s3 = 0.f;
    float s4 = 0.f, s5 = 0.f, s6 = 0.f, s7 = 0.f;
    int i = 0;
    for (; i + 8 <= c; i += 8) {
        int4 na = *(const int4*)(lst + i);
        int4 nb = *(const int4*)(lst + i + 4);
        float v0 = key2f(pooled16[(size_t)na.x * 64 + lane]);
        float v1 = key2f(pooled16[(size_t)na.y * 64 + lane]);
        float v2 = key2f(pooled16[(size_t)na.z * 64 + lane]);
        float v3 = key2f(pooled16[(size_t)na.w * 64 + lane]);
        float v4 = key2f(pooled16[(size_t)nb.x * 64 + lane]);
        float v5 = key2f(pooled16[(size_t)nb.y * 64 + lane]);
        float v6 = key2f(pooled16[(size_t)nb.z * 64 + lane]);
        float v7 = key2f(pooled16[(size_t)nb.w * 64 + lane]);
        s0 += fmaxf(fmaf(v0, scale, shift), 0.f);
        s1 += fmaxf(fmaf(v1, scale, shift), 0.f);
        s2 += fmaxf(fmaf(v2, scale, shift), 0.f);
        s3 += fmaxf(fmaf(v3, scale, shift), 0.f);
        s4 += fmaxf(fmaf(v4, scale, shift), 0.f);
        s5 += fmaxf(fmaf(v5, scale, shift), 0.f);
        s6 += fmaxf(fmaf(v6, scale, shift), 0.f);
        s7 += fmaxf(fmaf(v7, scale, shift), 0.f);
    }
    for (; i < c; ++i) {
        float v0 = key2f(pooled16[(size_t)lst[i] * 64 + lane]);
        s0 += fmaxf(fmaf(v0, scale, shift), 0.f);
    }
    float den = 1.f / fmaxf((float)cv, 1.f);
    out[(size_t)v * 67 + lane] = ((s0 + s1) + (s2 + s3) + (s4 + s5) + (s6 + s7)) * den;
    if (lane < 3) {
        float p0 = 0.f, p1 = 0.f, p2 = 0.f, p3 = 0.f;
        int j = 0;
        for (; j + 4 <= c; j += 4) {
            p0 += pos[(size_t)lst[j] * 3 + lane];
            p1 += pos[(size_t)lst[j + 1] * 3 + lane];
            p2 += pos[(size_t)lst[j + 2] * 3 + lane];
            p3 += pos[(size_t)lst[j + 3] * 3 + lane];
        }
        for (; j < c; ++j) p0 += pos[(size_t)lst[j] * 3 + lane];
        out[(size_t)v * 67 + 64 + lane] = (p0 + p1 + p2 + p3) * den;
    }
}

// ================= fallback path (R2-verified) ===============================
__global__ __launch_bounds__(256) void k0_fused_old(const float* __restrict__ x,
                                                    const float* __restrict__ W,
                                                    const float* __restrict__ bias,
                                                    unsigned short* __restrict__ h16,
                                                    float* __restrict__ partials, int n16,
                                                    const int* __restrict__ rows,
                                                    const int* __restrict__ cols,
                                                    int* __restrict__ cursor,
                                                    unsigned int* __restrict__ pairs,
                                                    float4* __restrict__ zero_zone,
                                                    int zero_n4) {
    __shared__ float sW[4096];
    __shared__ float red[2][4][64];
    __shared__ int lh[NBUCK];
    __shared__ int lpos[NBUCK];
    int t = threadIdx.x;
    int bid = blockIdx.x;

    if (bid >= 2 * GEMM_BLOCKS) {
        int zb = bid - 2 * GEMM_BLOCKS;
        float4 z = {0.f, 0.f, 0.f, 0.f};
        for (int i = zb * 256 + t; i < zero_n4; i += XTRA_BLOCKS * 256) zero_zone[i] = z;
        return;
    }

    if (bid & 1) {
        int bb = bid >> 1;
        for (int j = t; j < NBUCK; j += 256) lh[j] = 0;
        __syncthreads();
        int base = bb * 4096 + t * 16;
        int r[16], c[16];
#pragma unroll
        for (int g4 = 0; g4 < 4; ++g4) {
            int e = base + g4 * 4;
            int4 r4 = *(const int4*)(rows + e);
            int4 c4 = *(const int4*)(cols + e);
            r[g4 * 4 + 0] = r4.x; c[g4 * 4 + 0] = c4.x;
            r[g4 * 4 + 1] = r4.y; c[g4 * 4 + 1] = c4.y;
            r[g4 * 4 + 2] = r4.z; c[g4 * 4 + 2] = c4.z;
            r[g4 * 4 + 3] = r4.w; c[g4 * 4 + 3] = c4.w;
        }
#pragma unroll
        for (int i = 0; i < 16; ++i) atomicAdd(&lh[c[i] >> BSHIFT], 1);
        __syncthreads();
        for (int j = t; j < NBUCK; j += 256) lpos[j] = atomicAdd(&cursor[j], lh[j]);
        __syncthreads();
#pragma unroll
        for (int i = 0; i < 16; ++i) {
            int bkt = c[i] >> BSHIFT;
            int idx = atomicAdd(&lpos[bkt], 1);
            if (idx < CAP_OLD)
                pairs[(size_t)bkt * CAP_OLD + idx] =
                    ((unsigned int)r[i] << 8) | (unsigned int)(c[i] & (NODES_PER_BUCK - 1));
        }
        return;
    }

    int gb = bid >> 1;
    for (int i = t; i < 4096; i += 256) sW[i] = W[i];
    __syncthreads();
    int lane = t & 63;
    int w = t >> 6;
    int l15 = lane & 15;
    int q = lane >> 4;

    f16x8 bf[4][2];
#pragma unroll
    for (int t4 = 0; t4 < 4; ++t4)
#pragma unroll
        for (int kb = 0; kb < 2; ++kb)
#pragma unroll
            for (int i = 0; i < 8; ++i)
                bf[t4][kb][i] = (_Float16)sW[(kb * 32 + q * 8 + i) * 64 + t4 * 16 + l15];
    float bv[4];
#pragma unroll
    for (int t4 = 0; t4 < 4; ++t4) bv[t4] = bias[t4 * 16 + l15];

    float s[4] = {0.f, 0.f, 0.f, 0.f}, s2[4] = {0.f, 0.f, 0.f, 0.f};

    for (int g = gb * 4 + w; g < n16; g += GEMM_BLOCKS * 4) {
        int row0 = g * 16;
        const float* xp = x + (size_t)(row0 + l15) * 64 + q * 8;
        float4 xa = *(const float4*)(xp);
        float4 xb = *(const float4*)(xp + 4);
        float4 xc = *(const float4*)(xp + 32);
        float4 xd = *(const float4*)(xp + 36);
        gemm_step(row0, pack8(xa, xb), pack8(xc, xd), bf, bv, s, s2, h16, l15, q);
    }

#pragma unroll
    for (int t4 = 0; t4 < 4; ++t4) {
        s[t4] += __shfl_xor(s[t4], 16, 64);
        s[t4] += __shfl_xor(s[t4], 32, 64);
        s2[t4] += __shfl_xor(s2[t4], 16, 64);
        s2[t4] += __shfl_xor(s2[t4], 32, 64);
    }
    if (lane < 16) {
#pragma unroll
        for (int t4 = 0; t4 < 4; ++t4) {
            red[0][w][t4 * 16 + lane] = s[t4];
            red[1][w][t4 * 16 + lane] = s2[t4];
        }
    }
    __syncthreads();
    if (t < 128) {
        int c = t & 63;
        int which = t >> 6;
        float v = red[which][0][c] + red[which][1][c] + red[which][2][c] + red[which][3][c];
        partials[(size_t)gb * 128 + which * 64 + c] = v;
    }
}

__global__ __launch_bounds__(1024) void k3_finalize(const float* __restrict__ partials,
                                                    const float* __restrict__ gamma,
                                                    const float* __restrict__ beta,
                                                    float* __restrict__ stats2, float invN) {
    __shared__ float red[8][128];
    __shared__ float tot[128];
    int t = threadIdx.x;
    int c = t & 127;
    int g = t >> 7;
    float s = 0.f;
    for (int b = g; b < GEMM_BLOCKS; b += 8) s += partials[(size_t)b * 128 + c];
    red[g][c] = s;
    __syncthreads();
    if (t < 128) {
        float v = 0.f;
#pragma unroll
        for (int g2 = 0; g2 < 8; ++g2) v += red[g2][t];
        tot[t] = v;
    }
    __syncthreads();
    if (t < 64) {
        float mean = tot[t] * invN;
        float var = tot[64 + t] * invN - mean * mean;
        float sc = gamma[t] * rsqrtf(var + BN_EPS);
        stats2[t] = sc;
        stats2[64 + t] = beta[t] - mean * sc;
    }
}

__global__ __launch_bounds__(1024) void k_pool_old(const unsigned int* __restrict__ pairs_,
                                                   const int* __restrict__ cursor,
                                                   const unsigned short* __restrict__ h16,
                                                   const float* __restrict__ pos,
                                                   const float* __restrict__ stats2,
                                                   float* __restrict__ xs,
                                                   float* __restrict__ ps,
                                                   float* __restrict__ cnt) {
    __shared__ unsigned int tile[NODES_PER_BUCK * 64];
    int b = blockIdx.x;
    int t = threadIdx.x;
    int lane = t & 63;
    int w = t >> 6;
    float scale = stats2[lane];
    float shift = stats2[64 + lane];

    const unsigned int* src = (const unsigned int*)(h16 + (size_t)b * (NODES_PER_BUCK * 64));
#pragma unroll
    for (int k = 0; k < 8; ++k) {
        int i = t + k * 1024;
        unsigned int u = src[i];
        tile[2 * i] = u & 0xFFFFu;
        tile[2 * i + 1] = u >> 16;
    }
    __syncthreads();

    int cntE = min(cursor[b], CAP_OLD);
    int start = b * CAP_OLD;
    int end = start + cntE;
    int chunk = (cntE + 15) >> 4;
    int cs = start + w * chunk;
    int ce = min(cs + chunk, end);
    for (int j0 = cs; j0 < ce; j0 += 64) {
        int lim = min(64, ce - j0);
        unsigned int pk = (lane < lim) ? pairs_[j0 + lane] : 0u;
        int jj = 0;
        for (; jj + 16 <= lim; jj += 16) {
            unsigned int qv[16];
            unsigned short vv[16];
#pragma unroll
            for (int u = 0; u < 16; ++u)
                qv[u] = (unsigned int)__builtin_amdgcn_readlane((int)pk, jj + u);
#pragma unroll
            for (int u = 0; u < 16; ++u) vv[u] = h16[(size_t)(qv[u] >> 8) * 64 + lane];
#pragma unroll
            for (int u = 0; u < 16; ++u)
                atomicMax(&tile[((qv[u] & 255u) << 6) + lane], (unsigned int)vv[u]);
        }
        for (; jj < lim; ++jj) {
            unsigned int qq = (unsigned int)__builtin_amdgcn_readlane((int)pk, jj);
            unsigned int v = h16[(size_t)(qq >> 8) * 64 + lane];
            atomicMax(&tile[((qq & 255u) << 6) + lane], v);
        }
    }
    __syncthreads();

#pragma unroll
    for (int nl = 0; nl < NODES_PER_BUCK; nl += 16) {
        int node_l = nl + w;
        int c = (b << BSHIFT) + node_l;
        float px = pos[(size_t)c * 3 + 0];
        float py = pos[(size_t)c * 3 + 1];
        float pz = pos[(size_t)c * 3 + 2];
        int v0 = min(max((int)floorf(px * 2.f), 0), NVOX_DIM - 1);
        int v1 = min(max((int)floorf(py * 2.f), 0), NVOX_DIM - 1);
        int v2 = min(max((int)floorf(pz * 2.f), 0), NVOX_DIM - 1);
        int vox = (v0 * NVOX_DIM + v1) * NVOX_DIM + v2;
        float v = key2f(tile[(node_l << 6) + lane]);
        float val = fmaxf(fmaf(v, scale, shift), 0.f);
        atomicAdd(&xs[(size_t)vox * 64 + lane], val);
        if (lane < 3) atomicAdd(&ps[vox * 3 + lane], lane == 0 ? px : (lane == 1 ? py : pz));
        if (lane == 0) atomicAdd(&cnt[vox], 1.f);
    }
}

__global__ __launch_bounds__(256) void k7_out(const float* __restrict__ xs,
                                              const float* __restrict__ ps,
                                              const float* __restrict__ cnt,
                                              float* __restrict__ out, int total) {
    int idx = blockIdx.x * blockDim.x + threadIdx.x;
    if (idx >= total) return;
    int v = idx / 67;
    int c = idx - v * 67;
    float d = fmaxf(cnt[v], 1.f);
    float val = (c < 64) ? xs[(size_t)v * 64 + c] : ps[v * 3 + (c - 64)];
    out[idx] = val / d;
}

extern "C" void kernel_launch(void* const* d_in, const int* in_sizes, int n_in,
                              void* d_out, int out_size, void* d_ws, size_t ws_size,
                              hipStream_t stream) {
    const float* x     = (const float*)d_in[0];
    const float* pos   = (const float*)d_in[1];
    const int*   ei    = (const int*)d_in[2];
    const float* W     = (const float*)d_in[3];
    const float* b     = (const float*)d_in[4];
    const float* gamma = (const float*)d_in[5];
    const float* beta  = (const float*)d_in[6];
    float* out = (float*)d_out;

    const int n = in_sizes[0] / 64;   // 262144
    const int E = in_sizes[2] / 2;    // 4194304
    char* ws = (char*)d_ws;

    const size_t NEED_NEW = 70643712;
    if (ws_size >= NEED_NEW) {
        // Layout (bytes):
        //   h16      @ 0          : 33,554,432
        //   pairs    @ 33,554,432 : 33,554,432  (1024 x 8192 u32; reused as pooled16)
        //   partials @ 67,108,864 : 524,288
        //   stats2   @ 67,633,152 : 1,024
        //   cursor   @ 67,634,176 : 65,536      (1024 x 16-int line-padded)
        //   vcursor  @ 67,699,712 : 128,000     (8000 x 4-int padded)
        //   vlist    @ 67,827,712 : 2,816,000   -> end 70,643,712
        unsigned short* h16      = (unsigned short*)(ws + 0);
        unsigned int*   pairs    = (unsigned int*)(ws + 33554432);
        unsigned short* pooled16 = (unsigned short*)(ws + 33554432);
        float*          partials = (float*)(ws + 67108864);
        float*          stats2   = (float*)(ws + 67633152);
        int*            cursor   = (int*)(ws + 67634176);
        int*            vcursor  = (int*)(ws + 67699712);
        int*            vlist    = (int*)(ws + 67827712);

        k_zero<<<189, 256, 0, stream>>>(cursor, 48384);  // cursor + vcursor contiguous
        k_front<<<GEMM_BLOCKS + BIN_BLOCKS + XTRA_BLOCKS, 512, 0, stream>>>(
            x, W, b, h16, partials, n >> 4, ei, ei + E, cursor, pairs,
            pos, vcursor, vlist);
        k_pool_new<<<NBUCK + 1, 1024, 0, stream>>>(pairs, cursor, h16, stats2, pooled16,
                                                   partials, gamma, beta, 1.0f / (float)n);
        k_vox<<<NVOX / 4, 256, 0, stream>>>(pooled16, vlist, vcursor, pos, stats2, out);
    } else {
        // Fallback: R2-verified layout/path
        unsigned short* h16      = (unsigned short*)(ws + 0);
        unsigned int*   pairs    = (unsigned int*)(ws + 33554432);
        float*          partials = (float*)(ws + 54525952);
        float*          stats2   = (float*)(ws + 55050240);
        int*            cursor   = (int*)(ws + 55051264);
        float*          xs       = (float*)(ws + 55055360);
        float*          ps       = (float*)(ws + 57103360);
        float*          cnt      = (float*)(ws + 57199360);
        float4*         zero4    = (float4*)(ws + 55055360);
        const int zero_n4 = (57231360 - 55055360) / 16;

        k_zero<<<4, 256, 0, stream>>>(cursor, NBUCK);
        k0_fused_old<<<2 * GEMM_BLOCKS + XTRA_BLOCKS, 256, 0, stream>>>(
            x, W, b, h16, partials, n >> 4, ei, ei + E, cursor, pairs, zero4, zero_n4);
        k3_finalize<<<1, 1024, 0, stream>>>(partials, gamma, beta, stats2, 1.0f / (float)n);
        k_pool_old<<<NBUCK, 1024, 0, stream>>>(pairs, cursor, h16, pos, stats2, xs, ps, cnt);
        k7_out<<<(out_size + 255) / 256, 256, 0, stream>>>(xs, ps, cnt, out, out_size);
    }
}